// Round 3
// baseline (667.383 us; speedup 1.0000x reference)
//
#include <hip/hip_runtime.h>

#define NPTS 768
#define NBLK 960
#define SCALE 0.10206207261596575f  // 1/sqrt(96); attention uses natural-exp Taylor

// 1/t! for t=0..12 (natural exp Taylor)
static __device__ const float CFACT[13] = {
  1.0f, 1.0f, 0.5f, 0.16666667f, 0.041666668f, 0.008333334f, 0.0013888889f,
  1.9841270e-4f, 2.4801587e-5f, 2.7557319e-6f, 2.7557319e-7f, 2.5052108e-8f, 2.0876757e-9f
};

// Fast per-block grid barrier: ONE atomic arrival per block (cg::this_grid().sync()
// appears to do per-thread arrival -> ~230us; this should be ~2-5us).
// Release via ACQ_REL RMW; acquire via spin load + __threadfence() for cache inval.
__device__ __forceinline__ void grid_bar(unsigned int* cnt) {
  __syncthreads();
  if (threadIdx.x == 0) {
    __hip_atomic_fetch_add(cnt, 1u, __ATOMIC_ACQ_REL, __HIP_MEMORY_SCOPE_AGENT);
    while (__hip_atomic_load(cnt, __ATOMIC_ACQUIRE, __HIP_MEMORY_SCOPE_AGENT) < (unsigned)NBLK) {
      __builtin_amdgcn_s_sleep(2);
    }
  }
  __syncthreads();
  __threadfence();
}

// ====================== fused single-dispatch version ======================
// Phase A (== ka_pre split 192/384/384) -> bar -> Phase B (== kb_kv, 768 blocks,
// 2 pts/block, 2 waves/pt) -> bar -> Phase C (== kc_attn, 192 blocks).
// Co-residency: LDS 34816 -> 4 blocks/CU; 960 <= 256*4 = 1024.
__global__ __launch_bounds__(256, 4) void fused_all(
    const float* __restrict__ x, const float* __restrict__ y,
    const float* __restrict__ Wqf, const float* __restrict__ Wqd,
    const float* __restrict__ Wkf, const float* __restrict__ Wkd,
    const float* __restrict__ Wvf, const float* __restrict__ Wvd,
    float* __restrict__ qx, float* __restrict__ Pb, float* __restrict__ Rb,
    int* __restrict__ idxout, float* __restrict__ ksum, float* __restrict__ vsum,
    float* __restrict__ out, unsigned int* __restrict__ bar)
{
  __shared__ __align__(16) char smem[34816];
  int tid = threadIdx.x;
  int bid = blockIdx.x;

  // ---------------- Phase A ----------------
  if (bid < 192) {
    // ---------- Qx path: 8 points/block, 32 lanes/point ----------
    float2* w2 = (float2*)smem;
    float4 (*xs)[32] = (float4(*)[32])(smem + 8192);
    for (int i = tid; i < 1024; i += 256) {
      int cin = i >> 5, c = i & 31;
      w2[i] = make_float2(Wqf[c * 32 + cin], Wqd[c * 32 + cin]);
    }
    int g = tid >> 5, c = tid & 31;
    int p = bid * 8 + g;
    int b = p / NPTS, n = p % NPTS;
    for (int t = c; t < 96; t += 32) {
      float v = x[(b * 96 + t) * NPTS + n];
      ((float*)&xs[g][t / 3])[t % 3] = v;
    }
    __syncthreads();
    float pf0 = 0, pf1 = 0, pf2 = 0, pd0 = 0, pd1 = 0, pd2 = 0;
#pragma unroll
    for (int cin = 0; cin < 32; cin++) {
      float2 w = w2[(cin << 5) + c];
      float4 xv = xs[g][cin];
      pf0 = fmaf(w.x, xv.x, pf0); pf1 = fmaf(w.x, xv.y, pf1); pf2 = fmaf(w.x, xv.z, pf2);
      pd0 = fmaf(w.y, xv.x, pd0); pd1 = fmaf(w.y, xv.y, pd1); pd2 = fmaf(w.y, xv.z, pd2);
    }
    float dot = pf0 * pd0 + pf1 * pd1 + pf2 * pd2;
    float dsq = pd0 * pd0 + pd1 * pd1 + pd2 * pd2;
    float q0 = pf0, q1 = pf1, q2 = pf2;
    if (dot < 0.f) {
      float r = 0.8f * dot / (dsq + 1e-6f);
      q0 -= r * pd0; q1 -= r * pd1; q2 -= r * pd2;
    }
    float nrm = sqrtf(q0 * q0 + q1 * q1 + q2 * q2);
    float n2 = nrm * nrm;
#pragma unroll
    for (int m = 1; m <= 16; m <<= 1) n2 += __shfl_xor(n2, m);
    float fac = (nrm / fmaxf(sqrtf(n2), 1e-12f)) / fmaxf(nrm, 1e-12f);
    int base = ((b * 32 + c) * 3) * NPTS + n;
    qx[base] = q0 * fac; qx[base + NPTS] = q1 * fac; qx[base + 2 * NPTS] = q2 * fac;
  } else if (bid < 576) {
    // ---------- P/R path: 4 points/block, 64 lanes/point ----------
    float4* wLs = (float4*)smem;
    float4* wDs = (float4*)(smem + 16384);
    float4 (*xs)[32] = (float4(*)[32])(smem + 32768);
    for (int i = tid; i < 1024; i += 256) {
      int cin = i >> 5, c = i & 31;
      float kfL = Wkf[c * 64 + cin], kdL = Wkd[c * 64 + cin];
      float vfL = Wvf[c * 64 + cin], vdL = Wvd[c * 64 + cin];
      wLs[i] = make_float4(kfL, kdL, vfL, vdL);
      wDs[i] = make_float4(Wkf[c * 64 + 32 + cin] - kfL, Wkd[c * 64 + 32 + cin] - kdL,
                           Wvf[c * 64 + 32 + cin] - vfL, Wvd[c * 64 + 32 + cin] - vdL);
    }
    int g = tid >> 6, lane = tid & 63, half = lane >> 5, c = lane & 31;
    int p = (bid - 192) * 4 + g;
    int b = p / NPTS, n = p % NPTS;
    for (int t = lane; t < 96; t += 64) {
      float v = y[(b * 96 + t) * NPTS + n];
      ((float*)&xs[g][t / 3])[t % 3] = v;
    }
    __syncthreads();
    const float4* wsel = half ? wDs : wLs;
    float kf0 = 0, kf1 = 0, kf2 = 0, kd0 = 0, kd1 = 0, kd2 = 0;
    float vf0 = 0, vf1 = 0, vf2 = 0, vd0 = 0, vd1 = 0, vd2 = 0;
#pragma unroll 8
    for (int cin = 0; cin < 32; cin++) {
      float4 wv = wsel[(cin << 5) + c];
      float4 xv = xs[g][cin];
      kf0 = fmaf(wv.x, xv.x, kf0); kf1 = fmaf(wv.x, xv.y, kf1); kf2 = fmaf(wv.x, xv.z, kf2);
      kd0 = fmaf(wv.y, xv.x, kd0); kd1 = fmaf(wv.y, xv.y, kd1); kd2 = fmaf(wv.y, xv.z, kd2);
      vf0 = fmaf(wv.z, xv.x, vf0); vf1 = fmaf(wv.z, xv.y, vf1); vf2 = fmaf(wv.z, xv.z, vf2);
      vd0 = fmaf(wv.w, xv.x, vd0); vd1 = fmaf(wv.w, xv.y, vd1); vd2 = fmaf(wv.w, xv.z, vd2);
    }
    float* dst = half ? Rb : Pb;
    size_t base = ((size_t)(b * NPTS + n) * 32 + c) * 12;
    float4* Dp = (float4*)(dst + base);
    Dp[0] = make_float4(kf0, kf1, kf2, kd0);
    Dp[1] = make_float4(kd1, kd2, vf0, vf1);
    Dp[2] = make_float4(vf2, vd0, vd1, vd2);
  } else {
    // ---------- kNN path: 4 rows/block ----------
    float4 (*as4)[24] = (float4(*)[24])smem;
    unsigned int (*kd)[NPTS] = (unsigned int(*)[NPTS])(smem + 1536);
    int kb = bid - 576;
    int b = kb / 192;
    int n0 = (kb % 192) * 4;
    const float* yb = y + b * 96 * NPTS;
    for (int i = tid; i < 384; i += 256) {
      int j = i / 96, f = i % 96;
      ((float*)as4)[j * 96 + f] = yb[f * NPTS + n0 + j];
    }
    __syncthreads();
    float in[12];
    float sqm[3] = {0.f, 0.f, 0.f};
#pragma unroll
    for (int t = 0; t < 12; t++) in[t] = 0.f;
#pragma unroll 4
    for (int f4 = 0; f4 < 24; f4++) {
      float4 a0 = as4[0][f4], a1 = as4[1][f4], a2 = as4[2][f4], a3 = as4[3][f4];
#pragma unroll
      for (int r = 0; r < 3; r++) {
        int m = r * 256 + tid;
        const float* col = yb + (f4 * 4) * NPTS + m;
        float b0 = col[0], b1 = col[NPTS], b2 = col[2 * NPTS], b3 = col[3 * NPTS];
        sqm[r] = fmaf(b0, b0, fmaf(b1, b1, fmaf(b2, b2, fmaf(b3, b3, sqm[r]))));
        in[0 + r] = fmaf(a0.x, b0, fmaf(a0.y, b1, fmaf(a0.z, b2, fmaf(a0.w, b3, in[0 + r]))));
        in[3 + r] = fmaf(a1.x, b0, fmaf(a1.y, b1, fmaf(a1.z, b2, fmaf(a1.w, b3, in[3 + r]))));
        in[6 + r] = fmaf(a2.x, b0, fmaf(a2.y, b1, fmaf(a2.z, b2, fmaf(a2.w, b3, in[6 + r]))));
        in[9 + r] = fmaf(a3.x, b0, fmaf(a3.y, b1, fmaf(a3.z, b2, fmaf(a3.w, b3, in[9 + r]))));
      }
    }
#pragma unroll
    for (int j = 0; j < 4; j++) {
#pragma unroll
      for (int r = 0; r < 3; r++) {
        int m = r * 256 + tid;
        float v = 2.f * in[j * 3 + r] - sqm[r];
        unsigned int u = __float_as_uint(v);
        u = (u & 0x80000000u) ? ~u : (u | 0x80000000u);   // monotone map (exact)
        kd[j][m] = u;
      }
    }
    __syncthreads();
    int w = tid >> 6, lane = tid & 63;
    unsigned long long kk[12];
#pragma unroll
    for (int j = 0; j < 12; j++) {
      int m = lane + 64 * j;
      kk[j] = ((unsigned long long)kd[w][m] << 10) | (unsigned)(1023 - m);
    }
    int outbase = (b * NPTS + n0 + w) * 16;
    for (int it = 0; it < 16; it++) {
      unsigned long long a0 = kk[0] > kk[1] ? kk[0] : kk[1];
      unsigned long long a1 = kk[2] > kk[3] ? kk[2] : kk[3];
      unsigned long long a2 = kk[4] > kk[5] ? kk[4] : kk[5];
      unsigned long long a3 = kk[6] > kk[7] ? kk[6] : kk[7];
      unsigned long long a4 = kk[8] > kk[9] ? kk[8] : kk[9];
      unsigned long long a5 = kk[10] > kk[11] ? kk[10] : kk[11];
      unsigned long long b0 = a0 > a1 ? a0 : a1;
      unsigned long long b1 = a2 > a3 ? a2 : a3;
      unsigned long long b2 = a4 > a5 ? a4 : a5;
      unsigned long long best = b0 > b1 ? b0 : b1;
      best = best > b2 ? best : b2;
#pragma unroll
      for (int off = 1; off <= 32; off <<= 1) {
        unsigned long long o = __shfl_xor(best, off);
        best = o > best ? o : best;
      }
      int wm = 1023 - (int)(best & 1023u);
      if (lane == 0) idxout[outbase + it] = wm;
      int jj = wm >> 6;                 // wave-uniform
      bool me = (lane == (wm & 63));
      switch (jj) {
        case 0:  kk[0]  = me ? 0ull : kk[0];  break;
        case 1:  kk[1]  = me ? 0ull : kk[1];  break;
        case 2:  kk[2]  = me ? 0ull : kk[2];  break;
        case 3:  kk[3]  = me ? 0ull : kk[3];  break;
        case 4:  kk[4]  = me ? 0ull : kk[4];  break;
        case 5:  kk[5]  = me ? 0ull : kk[5];  break;
        case 6:  kk[6]  = me ? 0ull : kk[6];  break;
        case 7:  kk[7]  = me ? 0ull : kk[7];  break;
        case 8:  kk[8]  = me ? 0ull : kk[8];  break;
        case 9:  kk[9]  = me ? 0ull : kk[9];  break;
        case 10: kk[10] = me ? 0ull : kk[10]; break;
        default: kk[11] = me ? 0ull : kk[11]; break;
      }
    }
  }

  grid_bar(bar + 0);

  // ---------------- Phase B: gather + nonlinearity + accumulate ----------------
  // blocks 0..767: 2 points/block, 2 waves/point (latency-hiding structure from R2).
  if (bid < 768) {
    float (*red)[6][32] = (float(*)[6][32])smem;
    int w = tid >> 6;           // wave 0..3
    int pt = w >> 1;            // point slot within block
    int wh = w & 1;             // neighbor-group wave
    int lane = tid & 63, kh = lane >> 5, c = lane & 31;
    int p = bid * 2 + pt;
    int b = p / NPTS, n = p % NPTS;
    const float4* Rp = (const float4*)(Rb + ((size_t)(b * NPTS + n) * 32 + c) * 12);
    float4 r0 = Rp[0], r1 = Rp[1], r2 = Rp[2];
    int ibase = (b * NPTS + n) * 16 + wh * 8 + kh * 4;
    int4 ia = *(const int4*)(idxout + ibase);
    int ms[4] = {ia.x, ia.y, ia.z, ia.w};
    float ks0 = 0, ks1 = 0, ks2 = 0, vs0 = 0, vs1 = 0, vs2 = 0;
#pragma unroll
    for (int j = 0; j < 4; j++) {
      const float4* Pp = (const float4*)(Pb + ((size_t)(b * NPTS + ms[j]) * 32 + c) * 12);
      float4 p0 = Pp[0], p1 = Pp[1], p2 = Pp[2];
      float kf0 = p0.x + r0.x, kf1 = p0.y + r0.y, kf2 = p0.z + r0.z;
      float kd0 = p0.w + r0.w, kd1 = p1.x + r1.x, kd2 = p1.y + r1.y;
      float vf0 = p1.z + r1.z, vf1 = p1.w + r1.w, vf2 = p2.x + r2.x;
      float vd0 = p2.y + r2.y, vd1 = p2.z + r2.z, vd2 = p2.w + r2.w;
      float dot = kf0 * kd0 + kf1 * kd1 + kf2 * kd2;
      float dsq = kd0 * kd0 + kd1 * kd1 + kd2 * kd2;
      float k0 = kf0, k1 = kf1, k2 = kf2;
      if (dot < 0.f) { float r = 0.8f * dot / (dsq + 1e-6f); k0 -= r * kd0; k1 -= r * kd1; k2 -= r * kd2; }
      float nrm = sqrtf(k0 * k0 + k1 * k1 + k2 * k2);
      float n2 = nrm * nrm;
#pragma unroll
      for (int mm = 1; mm <= 16; mm <<= 1) n2 += __shfl_xor(n2, mm);
      float fac = (nrm / fmaxf(sqrtf(n2), 1e-12f)) / fmaxf(nrm, 1e-12f);
      ks0 = fmaf(k0, fac, ks0); ks1 = fmaf(k1, fac, ks1); ks2 = fmaf(k2, fac, ks2);
      float dotv = vf0 * vd0 + vf1 * vd1 + vf2 * vd2;
      float dsqv = vd0 * vd0 + vd1 * vd1 + vd2 * vd2;
      float v0 = vf0, v1 = vf1, v2 = vf2;
      if (dotv < 0.f) { float r = 0.8f * dotv / (dsqv + 1e-6f); v0 -= r * vd0; v1 -= r * vd1; v2 -= r * vd2; }
      vs0 += v0; vs1 += v1; vs2 += v2;
    }
    ks0 += __shfl_xor(ks0, 32); ks1 += __shfl_xor(ks1, 32); ks2 += __shfl_xor(ks2, 32);
    vs0 += __shfl_xor(vs0, 32); vs1 += __shfl_xor(vs1, 32); vs2 += __shfl_xor(vs2, 32);
    if (kh == 0 && wh == 1) {
      red[pt][0][c] = ks0; red[pt][1][c] = ks1; red[pt][2][c] = ks2;
      red[pt][3][c] = vs0; red[pt][4][c] = vs1; red[pt][5][c] = vs2;
    }
    __syncthreads();
    if (kh == 0 && wh == 0) {
      ks0 += red[pt][0][c]; ks1 += red[pt][1][c]; ks2 += red[pt][2][c];
      vs0 += red[pt][3][c]; vs1 += red[pt][4][c]; vs2 += red[pt][5][c];
      int base = ((b * 32 + c) * 3) * NPTS + n;
      ksum[base] = ks0 * SCALE; ksum[base + NPTS] = ks1 * SCALE; ksum[base + 2 * NPTS] = ks2 * SCALE;
      vsum[base] = vs0; vsum[base + NPTS] = vs1; vsum[base + 2 * NPTS] = vs2;
    }
  }

  grid_bar(bar + 1);

  // ---------------- Phase C: attention via Taylor power-moments ----------------
  if (bid < 192) {
    float (*redc)[25] = (float(*)[25])smem;      // 400 B
    float* AB = (float*)(smem + 512);            // AB[0..25]
    int sl = bid;
    const float* srow = ksum + sl * NPTS;
    const float* vrow = vsum + sl * NPTS;
    float P[12], Q[13];
#pragma unroll
    for (int t = 0; t < 12; t++) P[t] = 0.f;
#pragma unroll
    for (int t = 0; t < 13; t++) Q[t] = 0.f;
    for (int m = tid; m < NPTS; m += 256) {
      float s = srow[m], v = vrow[m];
      Q[0] += v;
      float pw = s;
#pragma unroll
      for (int t = 0; t < 12; t++) {
        P[t] += pw;
        Q[t + 1] = fmaf(pw, v, Q[t + 1]);
        pw *= s;
      }
    }
#pragma unroll
    for (int off = 1; off <= 32; off <<= 1) {
#pragma unroll
      for (int t = 0; t < 12; t++) P[t] += __shfl_xor(P[t], off);
#pragma unroll
      for (int t = 0; t < 13; t++) Q[t] += __shfl_xor(Q[t], off);
    }
    int lane = tid & 63, wid = tid >> 6;
    if (lane == 0) {
#pragma unroll
      for (int t = 0; t < 12; t++) redc[wid][t] = P[t];
#pragma unroll
      for (int t = 0; t < 13; t++) redc[wid][12 + t] = Q[t];
    }
    __syncthreads();
    if (tid < 25) {
      float sm = redc[0][tid] + redc[1][tid] + redc[2][tid] + redc[3][tid];
      if (tid < 12) AB[1 + tid] = CFACT[1 + tid] * sm;
      else          AB[13 + (tid - 12)] = CFACT[tid - 12] * sm;
    }
    if (tid == 25) AB[0] = (float)NPTS;
    __syncthreads();
#pragma unroll
    for (int nn = 0; nn < 3; nn++) {
      int n = nn * 256 + tid;
      float q = qx[sl * NPTS + n];
      float den = AB[12], num = AB[25];
#pragma unroll
      for (int t = 11; t >= 0; t--) {
        den = fmaf(den, q, AB[t]);
        num = fmaf(num, q, AB[13 + t]);
      }
      out[sl * NPTS + n] = x[sl * NPTS + n] + num / den;
    }
  }
}

// ====================== fallback: proven 3-kernel pipeline (R2, 114.5us) ======================
__global__ __launch_bounds__(256) void ka_pre(const float* __restrict__ x,
    const float* __restrict__ y,
    const float* __restrict__ Wqf, const float* __restrict__ Wqd,
    const float* __restrict__ Wkf, const float* __restrict__ Wkd,
    const float* __restrict__ Wvf, const float* __restrict__ Wvd,
    float* __restrict__ qx, float* __restrict__ Pb, float* __restrict__ Rb,
    int* __restrict__ idxout)
{
  __shared__ __align__(16) char smem[34816];
  int tid = threadIdx.x;
  if (blockIdx.x < 192) {
    float2* w2 = (float2*)smem;
    float4 (*xs)[32] = (float4(*)[32])(smem + 8192);
    for (int i = tid; i < 1024; i += 256) {
      int cin = i >> 5, c = i & 31;
      w2[i] = make_float2(Wqf[c * 32 + cin], Wqd[c * 32 + cin]);
    }
    int g = tid >> 5, c = tid & 31;
    int p = blockIdx.x * 8 + g;
    int b = p / NPTS, n = p % NPTS;
    for (int t = c; t < 96; t += 32) {
      float v = x[(b * 96 + t) * NPTS + n];
      ((float*)&xs[g][t / 3])[t % 3] = v;
    }
    __syncthreads();
    float pf0 = 0, pf1 = 0, pf2 = 0, pd0 = 0, pd1 = 0, pd2 = 0;
#pragma unroll
    for (int cin = 0; cin < 32; cin++) {
      float2 w = w2[(cin << 5) + c];
      float4 xv = xs[g][cin];
      pf0 = fmaf(w.x, xv.x, pf0); pf1 = fmaf(w.x, xv.y, pf1); pf2 = fmaf(w.x, xv.z, pf2);
      pd0 = fmaf(w.y, xv.x, pd0); pd1 = fmaf(w.y, xv.y, pd1); pd2 = fmaf(w.y, xv.z, pd2);
    }
    float dot = pf0 * pd0 + pf1 * pd1 + pf2 * pd2;
    float dsq = pd0 * pd0 + pd1 * pd1 + pd2 * pd2;
    float q0 = pf0, q1 = pf1, q2 = pf2;
    if (dot < 0.f) {
      float r = 0.8f * dot / (dsq + 1e-6f);
      q0 -= r * pd0; q1 -= r * pd1; q2 -= r * pd2;
    }
    float nrm = sqrtf(q0 * q0 + q1 * q1 + q2 * q2);
    float n2 = nrm * nrm;
#pragma unroll
    for (int m = 1; m <= 16; m <<= 1) n2 += __shfl_xor(n2, m);
    float fac = (nrm / fmaxf(sqrtf(n2), 1e-12f)) / fmaxf(nrm, 1e-12f);
    int base = ((b * 32 + c) * 3) * NPTS + n;
    qx[base] = q0 * fac; qx[base + NPTS] = q1 * fac; qx[base + 2 * NPTS] = q2 * fac;
  } else if (blockIdx.x < 576) {
    float4* wLs = (float4*)smem;
    float4* wDs = (float4*)(smem + 16384);
    float4 (*xs)[32] = (float4(*)[32])(smem + 32768);
    for (int i = tid; i < 1024; i += 256) {
      int cin = i >> 5, c = i & 31;
      float kfL = Wkf[c * 64 + cin], kdL = Wkd[c * 64 + cin];
      float vfL = Wvf[c * 64 + cin], vdL = Wvd[c * 64 + cin];
      wLs[i] = make_float4(kfL, kdL, vfL, vdL);
      wDs[i] = make_float4(Wkf[c * 64 + 32 + cin] - kfL, Wkd[c * 64 + 32 + cin] - kdL,
                           Wvf[c * 64 + 32 + cin] - vfL, Wvd[c * 64 + 32 + cin] - vdL);
    }
    int g = tid >> 6, lane = tid & 63, half = lane >> 5, c = lane & 31;
    int p = (blockIdx.x - 192) * 4 + g;
    int b = p / NPTS, n = p % NPTS;
    for (int t = lane; t < 96; t += 64) {
      float v = y[(b * 96 + t) * NPTS + n];
      ((float*)&xs[g][t / 3])[t % 3] = v;
    }
    __syncthreads();
    const float4* wsel = half ? wDs : wLs;
    float kf0 = 0, kf1 = 0, kf2 = 0, kd0 = 0, kd1 = 0, kd2 = 0;
    float vf0 = 0, vf1 = 0, vf2 = 0, vd0 = 0, vd1 = 0, vd2 = 0;
#pragma unroll 8
    for (int cin = 0; cin < 32; cin++) {
      float4 wv = wsel[(cin << 5) + c];
      float4 xv = xs[g][cin];
      kf0 = fmaf(wv.x, xv.x, kf0); kf1 = fmaf(wv.x, xv.y, kf1); kf2 = fmaf(wv.x, xv.z, kf2);
      kd0 = fmaf(wv.y, xv.x, kd0); kd1 = fmaf(wv.y, xv.y, kd1); kd2 = fmaf(wv.y, xv.z, kd2);
      vf0 = fmaf(wv.z, xv.x, vf0); vf1 = fmaf(wv.z, xv.y, vf1); vf2 = fmaf(wv.z, xv.z, vf2);
      vd0 = fmaf(wv.w, xv.x, vd0); vd1 = fmaf(wv.w, xv.y, vd1); vd2 = fmaf(wv.w, xv.z, vd2);
    }
    float* dst = half ? Rb : Pb;
    size_t base = ((size_t)(b * NPTS + n) * 32 + c) * 12;
    float4* Dp = (float4*)(dst + base);
    Dp[0] = make_float4(kf0, kf1, kf2, kd0);
    Dp[1] = make_float4(kd1, kd2, vf0, vf1);
    Dp[2] = make_float4(vf2, vd0, vd1, vd2);
  } else {
    float4 (*as4)[24] = (float4(*)[24])smem;
    unsigned int (*kd)[NPTS] = (unsigned int(*)[NPTS])(smem + 1536);
    int kb = blockIdx.x - 576;
    int b = kb / 192;
    int n0 = (kb % 192) * 4;
    const float* yb = y + b * 96 * NPTS;
    for (int i = tid; i < 384; i += 256) {
      int j = i / 96, f = i % 96;
      ((float*)as4)[j * 96 + f] = yb[f * NPTS + n0 + j];
    }
    __syncthreads();
    float in[12];
    float sqm[3] = {0.f, 0.f, 0.f};
#pragma unroll
    for (int t = 0; t < 12; t++) in[t] = 0.f;
#pragma unroll 4
    for (int f4 = 0; f4 < 24; f4++) {
      float4 a0 = as4[0][f4], a1 = as4[1][f4], a2 = as4[2][f4], a3 = as4[3][f4];
#pragma unroll
      for (int r = 0; r < 3; r++) {
        int m = r * 256 + tid;
        const float* col = yb + (f4 * 4) * NPTS + m;
        float b0 = col[0], b1 = col[NPTS], b2 = col[2 * NPTS], b3 = col[3 * NPTS];
        sqm[r] = fmaf(b0, b0, fmaf(b1, b1, fmaf(b2, b2, fmaf(b3, b3, sqm[r]))));
        in[0 + r] = fmaf(a0.x, b0, fmaf(a0.y, b1, fmaf(a0.z, b2, fmaf(a0.w, b3, in[0 + r]))));
        in[3 + r] = fmaf(a1.x, b0, fmaf(a1.y, b1, fmaf(a1.z, b2, fmaf(a1.w, b3, in[3 + r]))));
        in[6 + r] = fmaf(a2.x, b0, fmaf(a2.y, b1, fmaf(a2.z, b2, fmaf(a2.w, b3, in[6 + r]))));
        in[9 + r] = fmaf(a3.x, b0, fmaf(a3.y, b1, fmaf(a3.z, b2, fmaf(a3.w, b3, in[9 + r]))));
      }
    }
#pragma unroll
    for (int j = 0; j < 4; j++) {
#pragma unroll
      for (int r = 0; r < 3; r++) {
        int m = r * 256 + tid;
        float v = 2.f * in[j * 3 + r] - sqm[r];
        unsigned int u = __float_as_uint(v);
        u = (u & 0x80000000u) ? ~u : (u | 0x80000000u);
        kd[j][m] = u;
      }
    }
    __syncthreads();
    int w = tid >> 6, lane = tid & 63;
    unsigned long long kk[12];
#pragma unroll
    for (int j = 0; j < 12; j++) {
      int m = lane + 64 * j;
      kk[j] = ((unsigned long long)kd[w][m] << 10) | (unsigned)(1023 - m);
    }
    int outbase = (b * NPTS + n0 + w) * 16;
    for (int it = 0; it < 16; it++) {
      unsigned long long a0 = kk[0] > kk[1] ? kk[0] : kk[1];
      unsigned long long a1 = kk[2] > kk[3] ? kk[2] : kk[3];
      unsigned long long a2 = kk[4] > kk[5] ? kk[4] : kk[5];
      unsigned long long a3 = kk[6] > kk[7] ? kk[6] : kk[7];
      unsigned long long a4 = kk[8] > kk[9] ? kk[8] : kk[9];
      unsigned long long a5 = kk[10] > kk[11] ? kk[10] : kk[11];
      unsigned long long b0 = a0 > a1 ? a0 : a1;
      unsigned long long b1 = a2 > a3 ? a2 : a3;
      unsigned long long b2 = a4 > a5 ? a4 : a5;
      unsigned long long best = b0 > b1 ? b0 : b1;
      best = best > b2 ? best : b2;
#pragma unroll
      for (int off = 1; off <= 32; off <<= 1) {
        unsigned long long o = __shfl_xor(best, off);
        best = o > best ? o : best;
      }
      int wm = 1023 - (int)(best & 1023u);
      if (lane == 0) idxout[outbase + it] = wm;
      int jj = wm >> 6;
      bool me = (lane == (wm & 63));
      switch (jj) {
        case 0:  kk[0]  = me ? 0ull : kk[0];  break;
        case 1:  kk[1]  = me ? 0ull : kk[1];  break;
        case 2:  kk[2]  = me ? 0ull : kk[2];  break;
        case 3:  kk[3]  = me ? 0ull : kk[3];  break;
        case 4:  kk[4]  = me ? 0ull : kk[4];  break;
        case 5:  kk[5]  = me ? 0ull : kk[5];  break;
        case 6:  kk[6]  = me ? 0ull : kk[6];  break;
        case 7:  kk[7]  = me ? 0ull : kk[7];  break;
        case 8:  kk[8]  = me ? 0ull : kk[8];  break;
        case 9:  kk[9]  = me ? 0ull : kk[9];  break;
        case 10: kk[10] = me ? 0ull : kk[10]; break;
        default: kk[11] = me ? 0ull : kk[11]; break;
      }
    }
  }
}

__global__ __launch_bounds__(256) void kb_kv(const float* __restrict__ Pb,
    const float* __restrict__ Rb, const int* __restrict__ idxw,
    float* __restrict__ ksum, float* __restrict__ vsum)
{
  __shared__ float red[2][6][32];
  int tid = threadIdx.x;
  int w = tid >> 6;
  int pt = w >> 1;
  int wh = w & 1;
  int lane = tid & 63, kh = lane >> 5, c = lane & 31;
  int p = blockIdx.x * 2 + pt;
  int b = p / NPTS, n = p % NPTS;
  const float4* Rp = (const float4*)(Rb + ((size_t)(b * NPTS + n) * 32 + c) * 12);
  float4 r0 = Rp[0], r1 = Rp[1], r2 = Rp[2];
  int ibase = (b * NPTS + n) * 16 + wh * 8 + kh * 4;
  int4 ia = *(const int4*)(idxw + ibase);
  int ms[4] = {ia.x, ia.y, ia.z, ia.w};
  float ks0 = 0, ks1 = 0, ks2 = 0, vs0 = 0, vs1 = 0, vs2 = 0;
#pragma unroll
  for (int j = 0; j < 4; j++) {
    const float4* Pp = (const float4*)(Pb + ((size_t)(b * NPTS + ms[j]) * 32 + c) * 12);
    float4 p0 = Pp[0], p1 = Pp[1], p2 = Pp[2];
    float kf0 = p0.x + r0.x, kf1 = p0.y + r0.y, kf2 = p0.z + r0.z;
    float kd0 = p0.w + r0.w, kd1 = p1.x + r1.x, kd2 = p1.y + r1.y;
    float vf0 = p1.z + r1.z, vf1 = p1.w + r1.w, vf2 = p2.x + r2.x;
    float vd0 = p2.y + r2.y, vd1 = p2.z + r2.z, vd2 = p2.w + r2.w;
    float dot = kf0 * kd0 + kf1 * kd1 + kf2 * kd2;
    float dsq = kd0 * kd0 + kd1 * kd1 + kd2 * kd2;
    float k0 = kf0, k1 = kf1, k2 = kf2;
    if (dot < 0.f) { float r = 0.8f * dot / (dsq + 1e-6f); k0 -= r * kd0; k1 -= r * kd1; k2 -= r * kd2; }
    float nrm = sqrtf(k0 * k0 + k1 * k1 + k2 * k2);
    float n2 = nrm * nrm;
#pragma unroll
    for (int mm = 1; mm <= 16; mm <<= 1) n2 += __shfl_xor(n2, mm);
    float fac = (nrm / fmaxf(sqrtf(n2), 1e-12f)) / fmaxf(nrm, 1e-12f);
    ks0 = fmaf(k0, fac, ks0); ks1 = fmaf(k1, fac, ks1); ks2 = fmaf(k2, fac, ks2);
    float dotv = vf0 * vd0 + vf1 * vd1 + vf2 * vd2;
    float dsqv = vd0 * vd0 + vd1 * vd1 + vd2 * vd2;
    float v0 = vf0, v1 = vf1, v2 = vf2;
    if (dotv < 0.f) { float r = 0.8f * dotv / (dsqv + 1e-6f); v0 -= r * vd0; v1 -= r * vd1; v2 -= r * vd2; }
    vs0 += v0; vs1 += v1; vs2 += v2;
  }
  ks0 += __shfl_xor(ks0, 32); ks1 += __shfl_xor(ks1, 32); ks2 += __shfl_xor(ks2, 32);
  vs0 += __shfl_xor(vs0, 32); vs1 += __shfl_xor(vs1, 32); vs2 += __shfl_xor(vs2, 32);
  if (kh == 0 && wh == 1) {
    red[pt][0][c] = ks0; red[pt][1][c] = ks1; red[pt][2][c] = ks2;
    red[pt][3][c] = vs0; red[pt][4][c] = vs1; red[pt][5][c] = vs2;
  }
  __syncthreads();
  if (kh == 0 && wh == 0) {
    ks0 += red[pt][0][c]; ks1 += red[pt][1][c]; ks2 += red[pt][2][c];
    vs0 += red[pt][3][c]; vs1 += red[pt][4][c]; vs2 += red[pt][5][c];
    int base = ((b * 32 + c) * 3) * NPTS + n;
    ksum[base] = ks0 * SCALE; ksum[base + NPTS] = ks1 * SCALE; ksum[base + 2 * NPTS] = ks2 * SCALE;
    vsum[base] = vs0; vsum[base + NPTS] = vs1; vsum[base + 2 * NPTS] = vs2;
  }
}

__global__ __launch_bounds__(256) void kc_attn(const float* __restrict__ x,
    const float* __restrict__ qx, const float* __restrict__ ks, const float* __restrict__ vs,
    float* __restrict__ out)
{
  __shared__ float red[4][25];
  __shared__ float AB[26];
  int tid = threadIdx.x;
  int sl = blockIdx.x;
  const float* srow = ks + sl * NPTS;
  const float* vrow = vs + sl * NPTS;
  float P[12], Q[13];
#pragma unroll
  for (int t = 0; t < 12; t++) P[t] = 0.f;
#pragma unroll
  for (int t = 0; t < 13; t++) Q[t] = 0.f;
  for (int m = tid; m < NPTS; m += 256) {
    float s = srow[m], v = vrow[m];
    Q[0] += v;
    float pw = s;
#pragma unroll
    for (int t = 0; t < 12; t++) {
      P[t] += pw;
      Q[t + 1] = fmaf(pw, v, Q[t + 1]);
      pw *= s;
    }
  }
#pragma unroll
  for (int off = 1; off <= 32; off <<= 1) {
#pragma unroll
    for (int t = 0; t < 12; t++) P[t] += __shfl_xor(P[t], off);
#pragma unroll
    for (int t = 0; t < 13; t++) Q[t] += __shfl_xor(Q[t], off);
  }
  int lane = tid & 63, wid = tid >> 6;
  if (lane == 0) {
#pragma unroll
    for (int t = 0; t < 12; t++) red[wid][t] = P[t];
#pragma unroll
    for (int t = 0; t < 13; t++) red[wid][12 + t] = Q[t];
  }
  __syncthreads();
  if (tid < 25) {
    float sm = red[0][tid] + red[1][tid] + red[2][tid] + red[3][tid];
    if (tid < 12) AB[1 + tid] = CFACT[1 + tid] * sm;
    else          AB[13 + (tid - 12)] = CFACT[tid - 12] * sm;
  }
  if (tid == 25) AB[0] = (float)NPTS;
  __syncthreads();
#pragma unroll
  for (int nn = 0; nn < 3; nn++) {
    int n = nn * 256 + tid;
    float q = qx[sl * NPTS + n];
    float den = AB[12], num = AB[25];
#pragma unroll
    for (int t = 11; t >= 0; t--) {
      den = fmaf(den, q, AB[t]);
      num = fmaf(num, q, AB[13 + t]);
    }
    out[sl * NPTS + n] = x[sl * NPTS + n] + num / den;
  }
}

extern "C" void kernel_launch(void* const* d_in, const int* in_sizes, int n_in,
                              void* d_out, int out_size, void* d_ws, size_t ws_size,
                              hipStream_t stream) {
  const float* x   = (const float*)d_in[0];
  const float* y   = (const float*)d_in[1];
  const float* Wqf = (const float*)d_in[2];
  const float* Wqd = (const float*)d_in[3];
  const float* Wkf = (const float*)d_in[4];
  const float* Wkd = (const float*)d_in[5];
  const float* Wvf = (const float*)d_in[6];
  const float* Wvd = (const float*)d_in[7];
  float* out = (float*)d_out;

  float* qx   = (float*)d_ws;            // 147456
  float* ksum = qx + 147456;             // 147456 (pre-scaled by 1/sqrt(96))
  float* vsum = ksum + 147456;           // 147456
  int*   idx  = (int*)(vsum + 147456);   // 24576 ints
  float* Pb   = (float*)(idx + 24576);   // 589824
  float* Rb   = Pb + 589824;             // 589824
  unsigned int* bar = (unsigned int*)(Rb + 589824);  // 2 barrier counters

  hipMemsetAsync(bar, 0, 2 * sizeof(unsigned int), stream);

  void* args[] = { (void*)&x, (void*)&y, (void*)&Wqf, (void*)&Wqd, (void*)&Wkf, (void*)&Wkd,
                   (void*)&Wvf, (void*)&Wvd, (void*)&qx, (void*)&Pb, (void*)&Rb, (void*)&idx,
                   (void*)&ksum, (void*)&vsum, (void*)&out, (void*)&bar };
  hipError_t e = hipLaunchCooperativeKernel(reinterpret_cast<const void*>(&fused_all),
                                            dim3(NBLK), dim3(256), args, 0u, stream);
  if (e != hipSuccess) {
    // fallback: proven 3-dispatch pipeline (R2: 114.5 us)
    ka_pre <<<960, 256, 0, stream>>>(x, y, Wqf, Wqd, Wkf, Wkd, Wvf, Wvd, qx, Pb, Rb, idx);
    kb_kv  <<<768, 256, 0, stream>>>(Pb, Rb, idx, ksum, vsum);
    kc_attn<<<192, 256, 0, stream>>>(x, qx, ksum, vsum, out);
  }
}

// Round 4
// 123.394 us; speedup vs baseline: 5.4085x; 5.4085x over previous
//
#include <hip/hip_runtime.h>

#define NPTS 768
#define SCALE 0.10206207261596575f  // 1/sqrt(96); attention uses natural-exp Taylor

// 1/t! for t=0..12 (natural exp Taylor)
static __device__ const float CFACT[13] = {
  1.0f, 1.0f, 0.5f, 0.16666667f, 0.041666668f, 0.008333334f, 0.0013888889f,
  1.9841270e-4f, 2.4801587e-5f, 2.7557319e-6f, 2.7557319e-7f, 2.5052108e-8f, 2.0876757e-9f
};

// ---------------- KA: fused per-point transforms + kNN ----------------
// bid < 384   : P/R path (y -> Pb, Rb) + Qx path (x -> qx), 4 points/block, 64 lanes/point
// 384..575    : kNN top-16 path (y -> idx), 8 rows/block (halves y L2 traffic vs 4-row)
__global__ __launch_bounds__(256) void ka_pre(const float* __restrict__ x,
    const float* __restrict__ y,
    const float* __restrict__ Wqf, const float* __restrict__ Wqd,
    const float* __restrict__ Wkf, const float* __restrict__ Wkd,
    const float* __restrict__ Wvf, const float* __restrict__ Wvd,
    float* __restrict__ qx, float* __restrict__ Pb, float* __restrict__ Rb,
    int* __restrict__ idxout)
{
  __shared__ __align__(16) char smem[45056];
  int tid = threadIdx.x;
  if (blockIdx.x < 384) {
    // ---------- P/R path + Qx path (same 4 points) ----------
    float4* wLs = (float4*)smem;                        // 1024 entries, 16KB
    float4* wDs = (float4*)(smem + 16384);              // 1024 entries, 16KB
    float2* wq2 = (float2*)(smem + 32768);              // 1024 entries, 8KB
    float4 (*xs)[32] = (float4(*)[32])(smem + 40960);   // y rows [pt][cin], 2KB
    float4 (*xq)[32] = (float4(*)[32])(smem + 43008);   // x rows [pt][cin], 2KB
    for (int i = tid; i < 1024; i += 256) {
      int cin = i >> 5, c = i & 31;
      float kfL = Wkf[c * 64 + cin], kdL = Wkd[c * 64 + cin];
      float vfL = Wvf[c * 64 + cin], vdL = Wvd[c * 64 + cin];
      wLs[i] = make_float4(kfL, kdL, vfL, vdL);
      wDs[i] = make_float4(Wkf[c * 64 + 32 + cin] - kfL, Wkd[c * 64 + 32 + cin] - kdL,
                           Wvf[c * 64 + 32 + cin] - vfL, Wvd[c * 64 + 32 + cin] - vdL);
      wq2[i] = make_float2(Wqf[c * 32 + cin], Wqd[c * 32 + cin]);
    }
    int g = tid >> 6, lane = tid & 63, half = lane >> 5, c = lane & 31;
    int p = blockIdx.x * 4 + g;
    int b = p / NPTS, n = p % NPTS;
    for (int t = lane; t < 96; t += 64) {
      ((float*)&xs[g][t / 3])[t % 3] = y[(b * 96 + t) * NPTS + n];
      ((float*)&xq[g][t / 3])[t % 3] = x[(b * 96 + t) * NPTS + n];
    }
    __syncthreads();
    // ----- P/R (K/V linear halves) -----
    const float4* wsel = half ? wDs : wLs;
    float kf0 = 0, kf1 = 0, kf2 = 0, kd0 = 0, kd1 = 0, kd2 = 0;
    float vf0 = 0, vf1 = 0, vf2 = 0, vd0 = 0, vd1 = 0, vd2 = 0;
#pragma unroll 8
    for (int cin = 0; cin < 32; cin++) {
      float4 wv = wsel[(cin << 5) + c];
      float4 xv = xs[g][cin];
      kf0 = fmaf(wv.x, xv.x, kf0); kf1 = fmaf(wv.x, xv.y, kf1); kf2 = fmaf(wv.x, xv.z, kf2);
      kd0 = fmaf(wv.y, xv.x, kd0); kd1 = fmaf(wv.y, xv.y, kd1); kd2 = fmaf(wv.y, xv.z, kd2);
      vf0 = fmaf(wv.z, xv.x, vf0); vf1 = fmaf(wv.z, xv.y, vf1); vf2 = fmaf(wv.z, xv.z, vf2);
      vd0 = fmaf(wv.w, xv.x, vd0); vd1 = fmaf(wv.w, xv.y, vd1); vd2 = fmaf(wv.w, xv.z, vd2);
    }
    float* dst = half ? Rb : Pb;
    size_t base = ((size_t)(b * NPTS + n) * 32 + c) * 12;
    float4* Dp = (float4*)(dst + base);
    Dp[0] = make_float4(kf0, kf1, kf2, kd0);
    Dp[1] = make_float4(kd1, kd2, vf0, vf1);
    Dp[2] = make_float4(vf2, vd0, vd1, vd2);
    // ----- Qx (lanes 0..31 of each point-wave) -----
    if (half == 0) {
      float pf0 = 0, pf1 = 0, pf2 = 0, pd0 = 0, pd1 = 0, pd2 = 0;
#pragma unroll 8
      for (int cin = 0; cin < 32; cin++) {
        float2 w = wq2[(cin << 5) + c];
        float4 xv = xq[g][cin];
        pf0 = fmaf(w.x, xv.x, pf0); pf1 = fmaf(w.x, xv.y, pf1); pf2 = fmaf(w.x, xv.z, pf2);
        pd0 = fmaf(w.y, xv.x, pd0); pd1 = fmaf(w.y, xv.y, pd1); pd2 = fmaf(w.y, xv.z, pd2);
      }
      float dot = pf0 * pd0 + pf1 * pd1 + pf2 * pd2;
      float dsq = pd0 * pd0 + pd1 * pd1 + pd2 * pd2;
      float q0 = pf0, q1 = pf1, q2 = pf2;
      if (dot < 0.f) {
        float r = 0.8f * dot / (dsq + 1e-6f);
        q0 -= r * pd0; q1 -= r * pd1; q2 -= r * pd2;
      }
      float nrm = sqrtf(q0 * q0 + q1 * q1 + q2 * q2);
      float n2 = nrm * nrm;
#pragma unroll
      for (int m = 1; m <= 16; m <<= 1) n2 += __shfl_xor(n2, m);
      float fac = (nrm / fmaxf(sqrtf(n2), 1e-12f)) / fmaxf(nrm, 1e-12f);
      int qb = ((b * 32 + c) * 3) * NPTS + n;
      qx[qb] = q0 * fac; qx[qb + NPTS] = q1 * fac; qx[qb + 2 * NPTS] = q2 * fac;
    }
  } else {
    // ---------- kNN path: 8 rows/block ----------
    // Ranking within a row n needs only 2*inner - sq[m]  (sq[n] is a per-row constant shift).
    float4 (*as4)[24] = (float4(*)[24])smem;                 // [j][f4], 3KB
    unsigned int (*kd)[NPTS] = (unsigned int(*)[NPTS])(smem + 3072);  // [j][m], 24KB
    int kbn = blockIdx.x - 384;
    int b = kbn / 96;
    int n0 = (kbn % 96) * 8;
    const float* yb = y + b * 96 * NPTS;
    for (int i = tid; i < 768; i += 256) {
      int j = i / 96, f = i % 96;
      ((float*)as4)[j * 96 + f] = yb[f * NPTS + n0 + j];
    }
    __syncthreads();
    float in[24];                       // [j][r]
    float sqm[3] = {0.f, 0.f, 0.f};
#pragma unroll
    for (int t = 0; t < 24; t++) in[t] = 0.f;
#pragma unroll 2
    for (int f4 = 0; f4 < 24; f4++) {
      float4 a0 = as4[0][f4], a1 = as4[1][f4], a2 = as4[2][f4], a3 = as4[3][f4];
      float4 a4 = as4[4][f4], a5 = as4[5][f4], a6 = as4[6][f4], a7 = as4[7][f4];
#pragma unroll
      for (int r = 0; r < 3; r++) {
        int m = r * 256 + tid;
        const float* col = yb + (f4 * 4) * NPTS + m;
        float b0 = col[0], b1 = col[NPTS], b2 = col[2 * NPTS], b3 = col[3 * NPTS];
        sqm[r] = fmaf(b0, b0, fmaf(b1, b1, fmaf(b2, b2, fmaf(b3, b3, sqm[r]))));
        in[0 + r]  = fmaf(a0.x, b0, fmaf(a0.y, b1, fmaf(a0.z, b2, fmaf(a0.w, b3, in[0 + r]))));
        in[3 + r]  = fmaf(a1.x, b0, fmaf(a1.y, b1, fmaf(a1.z, b2, fmaf(a1.w, b3, in[3 + r]))));
        in[6 + r]  = fmaf(a2.x, b0, fmaf(a2.y, b1, fmaf(a2.z, b2, fmaf(a2.w, b3, in[6 + r]))));
        in[9 + r]  = fmaf(a3.x, b0, fmaf(a3.y, b1, fmaf(a3.z, b2, fmaf(a3.w, b3, in[9 + r]))));
        in[12 + r] = fmaf(a4.x, b0, fmaf(a4.y, b1, fmaf(a4.z, b2, fmaf(a4.w, b3, in[12 + r]))));
        in[15 + r] = fmaf(a5.x, b0, fmaf(a5.y, b1, fmaf(a5.z, b2, fmaf(a5.w, b3, in[15 + r]))));
        in[18 + r] = fmaf(a6.x, b0, fmaf(a6.y, b1, fmaf(a6.z, b2, fmaf(a6.w, b3, in[18 + r]))));
        in[21 + r] = fmaf(a7.x, b0, fmaf(a7.y, b1, fmaf(a7.z, b2, fmaf(a7.w, b3, in[21 + r]))));
      }
    }
#pragma unroll
    for (int j = 0; j < 8; j++) {
#pragma unroll
      for (int r = 0; r < 3; r++) {
        int m = r * 256 + tid;
        float v = 2.f * in[j * 3 + r] - sqm[r];
        unsigned int u = __float_as_uint(v);
        u = (u & 0x80000000u) ? ~u : (u | 0x80000000u);   // monotone map (exact)
        kd[j][m] = u;
      }
    }
    __syncthreads();
    int w = tid >> 6, lane = tid & 63;
    // each wave handles rows w and w+4 sequentially
    for (int rr = 0; rr < 2; rr++) {
      int row = w + rr * 4;
      unsigned long long kk[12];
#pragma unroll
      for (int j = 0; j < 12; j++) {
        int m = lane + 64 * j;
        kk[j] = ((unsigned long long)kd[row][m] << 10) | (unsigned)(1023 - m);
      }
      int outbase = (b * NPTS + n0 + row) * 16;
      for (int it = 0; it < 16; it++) {
        unsigned long long a0 = kk[0] > kk[1] ? kk[0] : kk[1];
        unsigned long long a1 = kk[2] > kk[3] ? kk[2] : kk[3];
        unsigned long long a2 = kk[4] > kk[5] ? kk[4] : kk[5];
        unsigned long long a3 = kk[6] > kk[7] ? kk[6] : kk[7];
        unsigned long long a4 = kk[8] > kk[9] ? kk[8] : kk[9];
        unsigned long long a5 = kk[10] > kk[11] ? kk[10] : kk[11];
        unsigned long long b0 = a0 > a1 ? a0 : a1;
        unsigned long long b1 = a2 > a3 ? a2 : a3;
        unsigned long long b2 = a4 > a5 ? a4 : a5;
        unsigned long long best = b0 > b1 ? b0 : b1;
        best = best > b2 ? best : b2;
#pragma unroll
        for (int off = 1; off <= 32; off <<= 1) {
          unsigned long long o = __shfl_xor(best, off);
          best = o > best ? o : best;
        }
        int wm = 1023 - (int)(best & 1023u);
        if (lane == 0) idxout[outbase + it] = wm;
        int jj = wm >> 6;                 // wave-uniform
        bool me = (lane == (wm & 63));
        switch (jj) {
          case 0:  kk[0]  = me ? 0ull : kk[0];  break;
          case 1:  kk[1]  = me ? 0ull : kk[1];  break;
          case 2:  kk[2]  = me ? 0ull : kk[2];  break;
          case 3:  kk[3]  = me ? 0ull : kk[3];  break;
          case 4:  kk[4]  = me ? 0ull : kk[4];  break;
          case 5:  kk[5]  = me ? 0ull : kk[5];  break;
          case 6:  kk[6]  = me ? 0ull : kk[6];  break;
          case 7:  kk[7]  = me ? 0ull : kk[7];  break;
          case 8:  kk[8]  = me ? 0ull : kk[8];  break;
          case 9:  kk[9]  = me ? 0ull : kk[9];  break;
          case 10: kk[10] = me ? 0ull : kk[10]; break;
          default: kk[11] = me ? 0ull : kk[11]; break;
        }
      }
    }
  }
}

// ---------------- KB: gather + nonlinearity + accumulate ----------------
// grid 768 x 256thr; block = 2 points; 2 waves/point (R2 latency-hiding structure).
// Wave wh of point pt handles neighbors wh*8..wh*8+7 (4 per lane-half kh).
// Cross-half combine via shfl_xor(32); cross-wave combine via LDS.
__global__ __launch_bounds__(256) void kb_kv(const float* __restrict__ Pb,
    const float* __restrict__ Rb, const int* __restrict__ idxw,
    float* __restrict__ ksum, float* __restrict__ vsum)
{
  __shared__ float red[2][6][32];
  int tid = threadIdx.x;
  int w = tid >> 6;           // wave 0..3
  int pt = w >> 1;            // point slot within block
  int wh = w & 1;             // neighbor-group wave
  int lane = tid & 63, kh = lane >> 5, c = lane & 31;
  int p = blockIdx.x * 2 + pt;
  int b = p / NPTS, n = p % NPTS;
  const float4* Rp = (const float4*)(Rb + ((size_t)(b * NPTS + n) * 32 + c) * 12);
  float4 r0 = Rp[0], r1 = Rp[1], r2 = Rp[2];
  int ibase = (b * NPTS + n) * 16 + wh * 8 + kh * 4;
  int4 ia = *(const int4*)(idxw + ibase);
  int ms[4] = {ia.x, ia.y, ia.z, ia.w};
  float ks0 = 0, ks1 = 0, ks2 = 0, vs0 = 0, vs1 = 0, vs2 = 0;
#pragma unroll
  for (int j = 0; j < 4; j++) {
    const float4* Pp = (const float4*)(Pb + ((size_t)(b * NPTS + ms[j]) * 32 + c) * 12);
    float4 p0 = Pp[0], p1 = Pp[1], p2 = Pp[2];
    float kf0 = p0.x + r0.x, kf1 = p0.y + r0.y, kf2 = p0.z + r0.z;
    float kd0 = p0.w + r0.w, kd1 = p1.x + r1.x, kd2 = p1.y + r1.y;
    float vf0 = p1.z + r1.z, vf1 = p1.w + r1.w, vf2 = p2.x + r2.x;
    float vd0 = p2.y + r2.y, vd1 = p2.z + r2.z, vd2 = p2.w + r2.w;
    float dot = kf0 * kd0 + kf1 * kd1 + kf2 * kd2;
    float dsq = kd0 * kd0 + kd1 * kd1 + kd2 * kd2;
    float k0 = kf0, k1 = kf1, k2 = kf2;
    if (dot < 0.f) { float r = 0.8f * dot / (dsq + 1e-6f); k0 -= r * kd0; k1 -= r * kd1; k2 -= r * kd2; }
    float nrm = sqrtf(k0 * k0 + k1 * k1 + k2 * k2);
    float n2 = nrm * nrm;
#pragma unroll
    for (int mm = 1; mm <= 16; mm <<= 1) n2 += __shfl_xor(n2, mm);
    float fac = (nrm / fmaxf(sqrtf(n2), 1e-12f)) / fmaxf(nrm, 1e-12f);
    ks0 = fmaf(k0, fac, ks0); ks1 = fmaf(k1, fac, ks1); ks2 = fmaf(k2, fac, ks2);
    float dotv = vf0 * vd0 + vf1 * vd1 + vf2 * vd2;
    float dsqv = vd0 * vd0 + vd1 * vd1 + vd2 * vd2;
    float v0 = vf0, v1 = vf1, v2 = vf2;
    if (dotv < 0.f) { float r = 0.8f * dotv / (dsqv + 1e-6f); v0 -= r * vd0; v1 -= r * vd1; v2 -= r * vd2; }
    vs0 += v0; vs1 += v1; vs2 += v2;
  }
  // combine the two lane-halves (neighbors j and j+4)
  ks0 += __shfl_xor(ks0, 32); ks1 += __shfl_xor(ks1, 32); ks2 += __shfl_xor(ks2, 32);
  vs0 += __shfl_xor(vs0, 32); vs1 += __shfl_xor(vs1, 32); vs2 += __shfl_xor(vs2, 32);
  // cross-wave combine: wave wh==1 publishes, wave wh==0 accumulates + writes
  if (kh == 0 && wh == 1) {
    red[pt][0][c] = ks0; red[pt][1][c] = ks1; red[pt][2][c] = ks2;
    red[pt][3][c] = vs0; red[pt][4][c] = vs1; red[pt][5][c] = vs2;
  }
  __syncthreads();
  if (kh == 0 && wh == 0) {
    ks0 += red[pt][0][c]; ks1 += red[pt][1][c]; ks2 += red[pt][2][c];
    vs0 += red[pt][3][c]; vs1 += red[pt][4][c]; vs2 += red[pt][5][c];
    int base = ((b * 32 + c) * 3) * NPTS + n;
    ksum[base] = ks0 * SCALE; ksum[base + NPTS] = ks1 * SCALE; ksum[base + 2 * NPTS] = ks2 * SCALE;
    vsum[base] = vs0; vsum[base + NPTS] = vs1; vsum[base + 2 * NPTS] = vs2;
  }
}

// ---------------- KC: attention via Taylor power-moments ----------------
// |q| <= 1, |s| <= 16/sqrt(96) = 1.633  ->  exp(q*s) Taylor deg-12, remainder < 1e-6.
// Per slice: P_t = sum_m s^t, Q_t = sum_m s^t v  (t<=12); per query: 24-fma Horner.
// One block per slice (192 blocks x 256 threads).
__global__ __launch_bounds__(256) void kc_attn(const float* __restrict__ x,
    const float* __restrict__ qx, const float* __restrict__ ks, const float* __restrict__ vs,
    float* __restrict__ out)
{
  __shared__ float red[4][25];
  __shared__ float AB[26];    // AB[0..12] = c_t*P_t (den coeffs), AB[13..25] = c_t*Q_t (num coeffs)
  int tid = threadIdx.x;
  int sl = blockIdx.x;
  const float* srow = ks + sl * NPTS;
  const float* vrow = vs + sl * NPTS;
  float P[12], Q[13];   // P[t] = sum s^{t+1};  Q[0] = sum v, Q[t] = sum s^t v
#pragma unroll
  for (int t = 0; t < 12; t++) P[t] = 0.f;
#pragma unroll
  for (int t = 0; t < 13; t++) Q[t] = 0.f;
  for (int m = tid; m < NPTS; m += 256) {
    float s = srow[m], v = vrow[m];
    Q[0] += v;
    float pw = s;
#pragma unroll
    for (int t = 0; t < 12; t++) {
      P[t] += pw;
      Q[t + 1] = fmaf(pw, v, Q[t + 1]);
      pw *= s;
    }
  }
#pragma unroll
  for (int off = 1; off <= 32; off <<= 1) {
#pragma unroll
    for (int t = 0; t < 12; t++) P[t] += __shfl_xor(P[t], off);
#pragma unroll
    for (int t = 0; t < 13; t++) Q[t] += __shfl_xor(Q[t], off);
  }
  int lane = tid & 63, wid = tid >> 6;
  if (lane == 0) {
#pragma unroll
    for (int t = 0; t < 12; t++) red[wid][t] = P[t];
#pragma unroll
    for (int t = 0; t < 13; t++) red[wid][12 + t] = Q[t];
  }
  __syncthreads();
  if (tid < 25) {
    float sm = red[0][tid] + red[1][tid] + red[2][tid] + red[3][tid];
    if (tid < 12) AB[1 + tid] = CFACT[1 + tid] * sm;          // A_t = P_t/t!, t=1..12
    else          AB[13 + (tid - 12)] = CFACT[tid - 12] * sm; // B_t = Q_t/t!, t=0..12
  }
  if (tid == 25) AB[0] = (float)NPTS;                          // A_0 = sum s^0
  __syncthreads();
#pragma unroll
  for (int nn = 0; nn < 3; nn++) {
    int n = nn * 256 + tid;
    float q = qx[sl * NPTS + n];
    float den = AB[12], num = AB[25];
#pragma unroll
    for (int t = 11; t >= 0; t--) {
      den = fmaf(den, q, AB[t]);
      num = fmaf(num, q, AB[13 + t]);
    }
    out[sl * NPTS + n] = x[sl * NPTS + n] + num / den;
  }
}

extern "C" void kernel_launch(void* const* d_in, const int* in_sizes, int n_in,
                              void* d_out, int out_size, void* d_ws, size_t ws_size,
                              hipStream_t stream) {
  const float* x   = (const float*)d_in[0];
  const float* y   = (const float*)d_in[1];
  const float* Wqf = (const float*)d_in[2];
  const float* Wqd = (const float*)d_in[3];
  const float* Wkf = (const float*)d_in[4];
  const float* Wkd = (const float*)d_in[5];
  const float* Wvf = (const float*)d_in[6];
  const float* Wvd = (const float*)d_in[7];
  float* out = (float*)d_out;

  float* qx   = (float*)d_ws;            // 147456
  float* ksum = qx + 147456;             // 147456 (pre-scaled by 1/sqrt(96))
  float* vsum = ksum + 147456;           // 147456
  int*   idx  = (int*)(vsum + 147456);   // 24576 ints
  float* Pb   = (float*)(idx + 24576);   // 589824
  float* Rb   = Pb + 589824;             // 589824

  ka_pre <<<576, 256, 0, stream>>>(x, y, Wqf, Wqd, Wkf, Wkd, Wvf, Wvd, qx, Pb, Rb, idx);
  kb_kv  <<<768, 256, 0, stream>>>(Pb, Rb, idx, ksum, vsum);
  kc_attn<<<192, 256, 0, stream>>>(x, qx, ksum, vsum, out);
}

// Round 5
// 107.645 us; speedup vs baseline: 6.1999x; 1.1463x over previous
//
#include <hip/hip_runtime.h>

#define NPTS 768
#define SCALE 0.10206207261596575f  // 1/sqrt(96); attention uses natural-exp Taylor

// 1/t! for t=0..12 (natural exp Taylor)
static __device__ const float CFACT[13] = {
  1.0f, 1.0f, 0.5f, 0.16666667f, 0.041666668f, 0.008333334f, 0.0013888889f,
  1.9841270e-4f, 2.4801587e-5f, 2.7557319e-6f, 2.7557319e-7f, 2.5052108e-8f, 2.0876757e-9f
};

// ---------------- KA: fused per-point transforms + kNN ----------------
// bid <  512 : kNN top-16 path (y -> idx), 3 rows/block, 512 blocks (2/CU even) — FIRST
//              so the long-pole blocks all start at t=0.
// 512..895   : P/R path (y -> Pb, Rb), 4 points/block, 64 lanes/point
// 896..1087  : Qx path (x -> qx), 8 points/block, 32 lanes/point
__global__ __launch_bounds__(256) void ka_pre(const float* __restrict__ x,
    const float* __restrict__ y,
    const float* __restrict__ Wqf, const float* __restrict__ Wqd,
    const float* __restrict__ Wkf, const float* __restrict__ Wkd,
    const float* __restrict__ Wvf, const float* __restrict__ Wvd,
    float* __restrict__ qx, float* __restrict__ Pb, float* __restrict__ Rb,
    int* __restrict__ idxout)
{
  __shared__ __align__(16) char smem[34816];
  int tid = threadIdx.x;
  if (blockIdx.x < 512) {
    // ---------- kNN path: 3 rows/block ----------
    // Ranking within a row n needs only 2*inner - sq[m]  (sq[n] is a per-row constant shift).
    // as4 rows padded to 100 floats (25 float4) to avoid staging bank conflicts.
    float4 (*as4)[25] = (float4(*)[25])smem;                     // 3*100 floats, 1200B
    unsigned int (*kd)[NPTS] = (unsigned int(*)[NPTS])(smem + 1280);  // [j][m], 9216B
    int kbn = blockIdx.x;
    int b = kbn >> 8;            // /256
    int n0 = (kbn & 255) * 3;
    const float* yb = y + b * 96 * NPTS;
    // coalesced-ish staging: 3 consecutive lanes read 12 contiguous bytes
    for (int i = tid; i < 288; i += 256) {
      int f = i / 3, j = i - f * 3;
      ((float*)smem)[j * 100 + f] = yb[f * NPTS + n0 + j];
    }
    __syncthreads();
    float in[9];                        // [j][r]
    float sqm[3] = {0.f, 0.f, 0.f};
#pragma unroll
    for (int t = 0; t < 9; t++) in[t] = 0.f;
#pragma unroll 4
    for (int f4 = 0; f4 < 24; f4++) {
      float4 a0 = as4[0][f4], a1 = as4[1][f4], a2 = as4[2][f4];
#pragma unroll
      for (int r = 0; r < 3; r++) {
        int m = r * 256 + tid;
        const float* col = yb + (f4 * 4) * NPTS + m;
        float b0 = col[0], b1 = col[NPTS], b2 = col[2 * NPTS], b3 = col[3 * NPTS];
        sqm[r] = fmaf(b0, b0, fmaf(b1, b1, fmaf(b2, b2, fmaf(b3, b3, sqm[r]))));
        in[0 + r] = fmaf(a0.x, b0, fmaf(a0.y, b1, fmaf(a0.z, b2, fmaf(a0.w, b3, in[0 + r]))));
        in[3 + r] = fmaf(a1.x, b0, fmaf(a1.y, b1, fmaf(a1.z, b2, fmaf(a1.w, b3, in[3 + r]))));
        in[6 + r] = fmaf(a2.x, b0, fmaf(a2.y, b1, fmaf(a2.z, b2, fmaf(a2.w, b3, in[6 + r]))));
      }
    }
#pragma unroll
    for (int j = 0; j < 3; j++) {
#pragma unroll
      for (int r = 0; r < 3; r++) {
        int m = r * 256 + tid;
        float v = 2.f * in[j * 3 + r] - sqm[r];
        unsigned int u = __float_as_uint(v);
        u = (u & 0x80000000u) ? ~u : (u | 0x80000000u);   // monotone map (exact)
        kd[j][m] = u;
      }
    }
    __syncthreads();
    int w = tid >> 6, lane = tid & 63;
    if (w < 3) {
      unsigned long long kk[12];
#pragma unroll
      for (int j = 0; j < 12; j++) {
        int m = lane + 64 * j;
        kk[j] = ((unsigned long long)kd[w][m] << 10) | (unsigned)(1023 - m);
      }
      int outbase = (b * NPTS + n0 + w) * 16;
      for (int it = 0; it < 16; it++) {
        unsigned long long a0 = kk[0] > kk[1] ? kk[0] : kk[1];
        unsigned long long a1 = kk[2] > kk[3] ? kk[2] : kk[3];
        unsigned long long a2 = kk[4] > kk[5] ? kk[4] : kk[5];
        unsigned long long a3 = kk[6] > kk[7] ? kk[6] : kk[7];
        unsigned long long a4 = kk[8] > kk[9] ? kk[8] : kk[9];
        unsigned long long a5 = kk[10] > kk[11] ? kk[10] : kk[11];
        unsigned long long b0 = a0 > a1 ? a0 : a1;
        unsigned long long b1 = a2 > a3 ? a2 : a3;
        unsigned long long b2 = a4 > a5 ? a4 : a5;
        unsigned long long best = b0 > b1 ? b0 : b1;
        best = best > b2 ? best : b2;
#pragma unroll
        for (int off = 1; off <= 32; off <<= 1) {
          unsigned long long o = __shfl_xor(best, off);
          best = o > best ? o : best;
        }
        int wm = 1023 - (int)(best & 1023u);
        if (lane == 0) idxout[outbase + it] = wm;
        int jj = wm >> 6;                 // wave-uniform
        bool me = (lane == (wm & 63));
        switch (jj) {
          case 0:  kk[0]  = me ? 0ull : kk[0];  break;
          case 1:  kk[1]  = me ? 0ull : kk[1];  break;
          case 2:  kk[2]  = me ? 0ull : kk[2];  break;
          case 3:  kk[3]  = me ? 0ull : kk[3];  break;
          case 4:  kk[4]  = me ? 0ull : kk[4];  break;
          case 5:  kk[5]  = me ? 0ull : kk[5];  break;
          case 6:  kk[6]  = me ? 0ull : kk[6];  break;
          case 7:  kk[7]  = me ? 0ull : kk[7];  break;
          case 8:  kk[8]  = me ? 0ull : kk[8];  break;
          case 9:  kk[9]  = me ? 0ull : kk[9];  break;
          case 10: kk[10] = me ? 0ull : kk[10]; break;
          default: kk[11] = me ? 0ull : kk[11]; break;
        }
      }
    }
  } else if (blockIdx.x < 896) {
    // ---------- P/R path ----------
    float4* wLs = (float4*)smem;                        // 1024 entries, 16KB
    float4* wDs = (float4*)(smem + 16384);              // 1024 entries, 16KB
    float4 (*xs)[32] = (float4(*)[32])(smem + 32768);   // [pt][cin], 2KB
    for (int i = tid; i < 1024; i += 256) {
      int cin = i >> 5, c = i & 31;
      float kfL = Wkf[c * 64 + cin], kdL = Wkd[c * 64 + cin];
      float vfL = Wvf[c * 64 + cin], vdL = Wvd[c * 64 + cin];
      wLs[i] = make_float4(kfL, kdL, vfL, vdL);
      wDs[i] = make_float4(Wkf[c * 64 + 32 + cin] - kfL, Wkd[c * 64 + 32 + cin] - kdL,
                           Wvf[c * 64 + 32 + cin] - vfL, Wvd[c * 64 + 32 + cin] - vdL);
    }
    int g = tid >> 6, lane = tid & 63, half = lane >> 5, c = lane & 31;
    int p = (blockIdx.x - 512) * 4 + g;
    int b = p / NPTS, n = p % NPTS;
    for (int t = lane; t < 96; t += 64) {
      float v = y[(b * 96 + t) * NPTS + n];
      ((float*)&xs[g][t / 3])[t % 3] = v;
    }
    __syncthreads();
    const float4* wsel = half ? wDs : wLs;
    float kf0 = 0, kf1 = 0, kf2 = 0, kd0 = 0, kd1 = 0, kd2 = 0;
    float vf0 = 0, vf1 = 0, vf2 = 0, vd0 = 0, vd1 = 0, vd2 = 0;
#pragma unroll 8
    for (int cin = 0; cin < 32; cin++) {
      float4 wv = wsel[(cin << 5) + c];
      float4 xv = xs[g][cin];
      kf0 = fmaf(wv.x, xv.x, kf0); kf1 = fmaf(wv.x, xv.y, kf1); kf2 = fmaf(wv.x, xv.z, kf2);
      kd0 = fmaf(wv.y, xv.x, kd0); kd1 = fmaf(wv.y, xv.y, kd1); kd2 = fmaf(wv.y, xv.z, kd2);
      vf0 = fmaf(wv.z, xv.x, vf0); vf1 = fmaf(wv.z, xv.y, vf1); vf2 = fmaf(wv.z, xv.z, vf2);
      vd0 = fmaf(wv.w, xv.x, vd0); vd1 = fmaf(wv.w, xv.y, vd1); vd2 = fmaf(wv.w, xv.z, vd2);
    }
    float* dst = half ? Rb : Pb;
    size_t base = ((size_t)(b * NPTS + n) * 32 + c) * 12;
    float4* Dp = (float4*)(dst + base);
    Dp[0] = make_float4(kf0, kf1, kf2, kd0);
    Dp[1] = make_float4(kd1, kd2, vf0, vf1);
    Dp[2] = make_float4(vf2, vd0, vd1, vd2);
  } else {
    // ---------- Qx path ----------
    float2* w2 = (float2*)smem;                       // [cin][c] (Wqf, Wqd), 8KB
    float4 (*xs)[32] = (float4(*)[32])(smem + 8192);  // [group][cin], 4KB
    for (int i = tid; i < 1024; i += 256) {
      int cin = i >> 5, c = i & 31;
      w2[i] = make_float2(Wqf[c * 32 + cin], Wqd[c * 32 + cin]);
    }
    int g = tid >> 5, c = tid & 31;
    int p = (blockIdx.x - 896) * 8 + g;
    int b = p / NPTS, n = p % NPTS;
    for (int t = c; t < 96; t += 32) {
      float v = x[(b * 96 + t) * NPTS + n];
      ((float*)&xs[g][t / 3])[t % 3] = v;
    }
    __syncthreads();
    float pf0 = 0, pf1 = 0, pf2 = 0, pd0 = 0, pd1 = 0, pd2 = 0;
#pragma unroll
    for (int cin = 0; cin < 32; cin++) {
      float2 w = w2[(cin << 5) + c];
      float4 xv = xs[g][cin];
      pf0 = fmaf(w.x, xv.x, pf0); pf1 = fmaf(w.x, xv.y, pf1); pf2 = fmaf(w.x, xv.z, pf2);
      pd0 = fmaf(w.y, xv.x, pd0); pd1 = fmaf(w.y, xv.y, pd1); pd2 = fmaf(w.y, xv.z, pd2);
    }
    float dot = pf0 * pd0 + pf1 * pd1 + pf2 * pd2;
    float dsq = pd0 * pd0 + pd1 * pd1 + pd2 * pd2;
    float q0 = pf0, q1 = pf1, q2 = pf2;
    if (dot < 0.f) {
      float r = 0.8f * dot / (dsq + 1e-6f);
      q0 -= r * pd0; q1 -= r * pd1; q2 -= r * pd2;
    }
    float nrm = sqrtf(q0 * q0 + q1 * q1 + q2 * q2);
    float n2 = nrm * nrm;
#pragma unroll
    for (int m = 1; m <= 16; m <<= 1) n2 += __shfl_xor(n2, m);
    float fac = (nrm / fmaxf(sqrtf(n2), 1e-12f)) / fmaxf(nrm, 1e-12f);
    int base = ((b * 32 + c) * 3) * NPTS + n;
    qx[base] = q0 * fac; qx[base + NPTS] = q1 * fac; qx[base + 2 * NPTS] = q2 * fac;
  }
}

// ---------------- KB: gather + nonlinearity + accumulate ----------------
// grid 768 x 256thr; block = 2 points; 2 waves/point (R2 latency-hiding structure).
// Wave wh of point pt handles neighbors wh*8..wh*8+7 (4 per lane-half kh).
// Cross-half combine via shfl_xor(32); cross-wave combine via LDS.
__global__ __launch_bounds__(256) void kb_kv(const float* __restrict__ Pb,
    const float* __restrict__ Rb, const int* __restrict__ idxw,
    float* __restrict__ ksum, float* __restrict__ vsum)
{
  __shared__ float red[2][6][32];
  int tid = threadIdx.x;
  int w = tid >> 6;           // wave 0..3
  int pt = w >> 1;            // point slot within block
  int wh = w & 1;             // neighbor-group wave
  int lane = tid & 63, kh = lane >> 5, c = lane & 31;
  int p = blockIdx.x * 2 + pt;
  int b = p / NPTS, n = p % NPTS;
  const float4* Rp = (const float4*)(Rb + ((size_t)(b * NPTS + n) * 32 + c) * 12);
  float4 r0 = Rp[0], r1 = Rp[1], r2 = Rp[2];
  int ibase = (b * NPTS + n) * 16 + wh * 8 + kh * 4;
  int4 ia = *(const int4*)(idxw + ibase);
  int ms[4] = {ia.x, ia.y, ia.z, ia.w};
  float ks0 = 0, ks1 = 0, ks2 = 0, vs0 = 0, vs1 = 0, vs2 = 0;
#pragma unroll
  for (int j = 0; j < 4; j++) {
    const float4* Pp = (const float4*)(Pb + ((size_t)(b * NPTS + ms[j]) * 32 + c) * 12);
    float4 p0 = Pp[0], p1 = Pp[1], p2 = Pp[2];
    float kf0 = p0.x + r0.x, kf1 = p0.y + r0.y, kf2 = p0.z + r0.z;
    float kd0 = p0.w + r0.w, kd1 = p1.x + r1.x, kd2 = p1.y + r1.y;
    float vf0 = p1.z + r1.z, vf1 = p1.w + r1.w, vf2 = p2.x + r2.x;
    float vd0 = p2.y + r2.y, vd1 = p2.z + r2.z, vd2 = p2.w + r2.w;
    float dot = kf0 * kd0 + kf1 * kd1 + kf2 * kd2;
    float dsq = kd0 * kd0 + kd1 * kd1 + kd2 * kd2;
    float k0 = kf0, k1 = kf1, k2 = kf2;
    if (dot < 0.f) { float r = 0.8f * dot / (dsq + 1e-6f); k0 -= r * kd0; k1 -= r * kd1; k2 -= r * kd2; }
    float nrm = sqrtf(k0 * k0 + k1 * k1 + k2 * k2);
    float n2 = nrm * nrm;
#pragma unroll
    for (int mm = 1; mm <= 16; mm <<= 1) n2 += __shfl_xor(n2, mm);
    float fac = (nrm / fmaxf(sqrtf(n2), 1e-12f)) / fmaxf(nrm, 1e-12f);
    ks0 = fmaf(k0, fac, ks0); ks1 = fmaf(k1, fac, ks1); ks2 = fmaf(k2, fac, ks2);
    float dotv = vf0 * vd0 + vf1 * vd1 + vf2 * vd2;
    float dsqv = vd0 * vd0 + vd1 * vd1 + vd2 * vd2;
    float v0 = vf0, v1 = vf1, v2 = vf2;
    if (dotv < 0.f) { float r = 0.8f * dotv / (dsqv + 1e-6f); v0 -= r * vd0; v1 -= r * vd1; v2 -= r * vd2; }
    vs0 += v0; vs1 += v1; vs2 += v2;
  }
  // combine the two lane-halves (neighbors j and j+4)
  ks0 += __shfl_xor(ks0, 32); ks1 += __shfl_xor(ks1, 32); ks2 += __shfl_xor(ks2, 32);
  vs0 += __shfl_xor(vs0, 32); vs1 += __shfl_xor(vs1, 32); vs2 += __shfl_xor(vs2, 32);
  // cross-wave combine: wave wh==1 publishes, wave wh==0 accumulates + writes
  if (kh == 0 && wh == 1) {
    red[pt][0][c] = ks0; red[pt][1][c] = ks1; red[pt][2][c] = ks2;
    red[pt][3][c] = vs0; red[pt][4][c] = vs1; red[pt][5][c] = vs2;
  }
  __syncthreads();
  if (kh == 0 && wh == 0) {
    ks0 += red[pt][0][c]; ks1 += red[pt][1][c]; ks2 += red[pt][2][c];
    vs0 += red[pt][3][c]; vs1 += red[pt][4][c]; vs2 += red[pt][5][c];
    int base = ((b * 32 + c) * 3) * NPTS + n;
    ksum[base] = ks0 * SCALE; ksum[base + NPTS] = ks1 * SCALE; ksum[base + 2 * NPTS] = ks2 * SCALE;
    vsum[base] = vs0; vsum[base + NPTS] = vs1; vsum[base + 2 * NPTS] = vs2;
  }
}

// ---------------- KC: attention via Taylor power-moments ----------------
// |q| <= 1, |s| <= 16/sqrt(96) = 1.633  ->  exp(q*s) Taylor deg-12, remainder < 1e-6.
// Per slice: P_t = sum_m s^t, Q_t = sum_m s^t v  (t<=12); per query: 24-fma Horner.
// One block per slice (192 blocks x 256 threads).
__global__ __launch_bounds__(256) void kc_attn(const float* __restrict__ x,
    const float* __restrict__ qx, const float* __restrict__ ks, const float* __restrict__ vs,
    float* __restrict__ out)
{
  __shared__ float red[4][25];
  __shared__ float AB[26];    // AB[0..12] = c_t*P_t (den coeffs), AB[13..25] = c_t*Q_t (num coeffs)
  int tid = threadIdx.x;
  int sl = blockIdx.x;
  const float* srow = ks + sl * NPTS;
  const float* vrow = vs + sl * NPTS;
  float P[12], Q[13];   // P[t] = sum s^{t+1};  Q[0] = sum v, Q[t] = sum s^t v
#pragma unroll
  for (int t = 0; t < 12; t++) P[t] = 0.f;
#pragma unroll
  for (int t = 0; t < 13; t++) Q[t] = 0.f;
  for (int m = tid; m < NPTS; m += 256) {
    float s = srow[m], v = vrow[m];
    Q[0] += v;
    float pw = s;
#pragma unroll
    for (int t = 0; t < 12; t++) {
      P[t] += pw;
      Q[t + 1] = fmaf(pw, v, Q[t + 1]);
      pw *= s;
    }
  }
#pragma unroll
  for (int off = 1; off <= 32; off <<= 1) {
#pragma unroll
    for (int t = 0; t < 12; t++) P[t] += __shfl_xor(P[t], off);
#pragma unroll
    for (int t = 0; t < 13; t++) Q[t] += __shfl_xor(Q[t], off);
  }
  int lane = tid & 63, wid = tid >> 6;
  if (lane == 0) {
#pragma unroll
    for (int t = 0; t < 12; t++) red[wid][t] = P[t];
#pragma unroll
    for (int t = 0; t < 13; t++) red[wid][12 + t] = Q[t];
  }
  __syncthreads();
  if (tid < 25) {
    float sm = red[0][tid] + red[1][tid] + red[2][tid] + red[3][tid];
    if (tid < 12) AB[1 + tid] = CFACT[1 + tid] * sm;          // A_t = P_t/t!, t=1..12
    else          AB[13 + (tid - 12)] = CFACT[tid - 12] * sm; // B_t = Q_t/t!, t=0..12
  }
  if (tid == 25) AB[0] = (float)NPTS;                          // A_0 = sum s^0
  __syncthreads();
#pragma unroll
  for (int nn = 0; nn < 3; nn++) {
    int n = nn * 256 + tid;
    float q = qx[sl * NPTS + n];
    float den = AB[12], num = AB[25];
#pragma unroll
    for (int t = 11; t >= 0; t--) {
      den = fmaf(den, q, AB[t]);
      num = fmaf(num, q, AB[13 + t]);
    }
    out[sl * NPTS + n] = x[sl * NPTS + n] + num / den;
  }
}

extern "C" void kernel_launch(void* const* d_in, const int* in_sizes, int n_in,
                              void* d_out, int out_size, void* d_ws, size_t ws_size,
                              hipStream_t stream) {
  const float* x   = (const float*)d_in[0];
  const float* y   = (const float*)d_in[1];
  const float* Wqf = (const float*)d_in[2];
  const float* Wqd = (const float*)d_in[3];
  const float* Wkf = (const float*)d_in[4];
  const float* Wkd = (const float*)d_in[5];
  const float* Wvf = (const float*)d_in[6];
  const float* Wvd = (const float*)d_in[7];
  float* out = (float*)d_out;

  float* qx   = (float*)d_ws;            // 147456
  float* ksum = qx + 147456;             // 147456 (pre-scaled by 1/sqrt(96))
  float* vsum = ksum + 147456;           // 147456
  int*   idx  = (int*)(vsum + 147456);   // 24576 ints
  float* Pb   = (float*)(idx + 24576);   // 589824
  float* Rb   = Pb + 589824;             // 589824

  ka_pre <<<1088, 256, 0, stream>>>(x, y, Wqf, Wqd, Wkf, Wkd, Wvf, Wvd, qx, Pb, Rb, idx);
  kb_kv  <<<768, 256, 0, stream>>>(Pb, Rb, idx, ksum, vsum);
  kc_attn<<<192, 256, 0, stream>>>(x, qx, ksum, vsum, out);
}

// Round 6
// 105.344 us; speedup vs baseline: 6.3353x; 1.0218x over previous
//
#include <hip/hip_runtime.h>

#define NPTS 768
#define SCALE 0.10206207261596575f  // 1/sqrt(96); attention uses natural-exp Taylor

// 1/t! for t=0..12 (natural exp Taylor)
static __device__ const float CFACT[13] = {
  1.0f, 1.0f, 0.5f, 0.16666667f, 0.041666668f, 0.008333334f, 0.0013888889f,
  1.9841270e-4f, 2.4801587e-5f, 2.7557319e-6f, 2.7557319e-7f, 2.5052108e-8f, 2.0876757e-9f
};

// ---------------- KA: fused per-point transforms + kNN ----------------
// bid <  768 : kNN top-16 path (y -> idx), 2 rows/block (3/CU even) — FIRST (long pole)
// 768..1151  : P/R path (y -> Pb, Rb), 4 points/block, 64 lanes/point
// 1152..1343 : Qx path (x -> qx), 8 points/block, 32 lanes/point
__global__ __launch_bounds__(256) void ka_pre(const float* __restrict__ x,
    const float* __restrict__ y,
    const float* __restrict__ Wqf, const float* __restrict__ Wqd,
    const float* __restrict__ Wkf, const float* __restrict__ Wkd,
    const float* __restrict__ Wvf, const float* __restrict__ Wvd,
    float* __restrict__ qx, float* __restrict__ Pb, float* __restrict__ Rb,
    int* __restrict__ idxout)
{
  __shared__ __align__(16) char smem[34816];
  int tid = threadIdx.x;
  if (blockIdx.x < 768) {
    // ---------- kNN path: 2 rows/block ----------
    // Ranking within a row n needs only 2*inner - sq[m]  (sq[n] is a per-row constant shift).
    // as4 rows padded to 100 floats (25 float4) to avoid staging bank conflicts.
    float4 (*as4)[25] = (float4(*)[25])smem;                     // 2*100 floats, 800B
    unsigned int (*kd)[NPTS] = (unsigned int(*)[NPTS])(smem + 1024);  // [j][m], 6144B
    int kbn = blockIdx.x;
    int b = kbn / 384;
    int n0 = (kbn % 384) * 2;
    const float* yb = y + b * 96 * NPTS;
    // staging: 2 consecutive lanes read 8 contiguous bytes
    for (int i = tid; i < 192; i += 256) {
      int f = i >> 1, j = i & 1;
      ((float*)smem)[j * 100 + f] = yb[f * NPTS + n0 + j];
    }
    __syncthreads();
    float in[6];                        // [j][r]
    float sqm[3] = {0.f, 0.f, 0.f};
#pragma unroll
    for (int t = 0; t < 6; t++) in[t] = 0.f;
#pragma unroll 4
    for (int f4 = 0; f4 < 24; f4++) {
      float4 a0 = as4[0][f4], a1 = as4[1][f4];
#pragma unroll
      for (int r = 0; r < 3; r++) {
        int m = r * 256 + tid;
        const float* col = yb + (f4 * 4) * NPTS + m;
        float b0 = col[0], b1 = col[NPTS], b2 = col[2 * NPTS], b3 = col[3 * NPTS];
        sqm[r] = fmaf(b0, b0, fmaf(b1, b1, fmaf(b2, b2, fmaf(b3, b3, sqm[r]))));
        in[0 + r] = fmaf(a0.x, b0, fmaf(a0.y, b1, fmaf(a0.z, b2, fmaf(a0.w, b3, in[0 + r]))));
        in[3 + r] = fmaf(a1.x, b0, fmaf(a1.y, b1, fmaf(a1.z, b2, fmaf(a1.w, b3, in[3 + r]))));
      }
    }
#pragma unroll
    for (int j = 0; j < 2; j++) {
#pragma unroll
      for (int r = 0; r < 3; r++) {
        int m = r * 256 + tid;
        float v = 2.f * in[j * 3 + r] - sqm[r];
        unsigned int u = __float_as_uint(v);
        u = (u & 0x80000000u) ? ~u : (u | 0x80000000u);   // monotone map (exact)
        kd[j][m] = u;
      }
    }
    __syncthreads();
    int w = tid >> 6, lane = tid & 63;
    if (w < 2) {
      unsigned long long kk[12];
#pragma unroll
      for (int j = 0; j < 12; j++) {
        int m = lane + 64 * j;
        kk[j] = ((unsigned long long)kd[w][m] << 10) | (unsigned)(1023 - m);
      }
      int outbase = (b * NPTS + n0 + w) * 16;
      for (int it = 0; it < 16; it++) {
        unsigned long long a0 = kk[0] > kk[1] ? kk[0] : kk[1];
        unsigned long long a1 = kk[2] > kk[3] ? kk[2] : kk[3];
        unsigned long long a2 = kk[4] > kk[5] ? kk[4] : kk[5];
        unsigned long long a3 = kk[6] > kk[7] ? kk[6] : kk[7];
        unsigned long long a4 = kk[8] > kk[9] ? kk[8] : kk[9];
        unsigned long long a5 = kk[10] > kk[11] ? kk[10] : kk[11];
        unsigned long long b0 = a0 > a1 ? a0 : a1;
        unsigned long long b1 = a2 > a3 ? a2 : a3;
        unsigned long long b2 = a4 > a5 ? a4 : a5;
        unsigned long long best = b0 > b1 ? b0 : b1;
        best = best > b2 ? best : b2;
#pragma unroll
        for (int off = 1; off <= 32; off <<= 1) {
          unsigned long long o = __shfl_xor(best, off);
          best = o > best ? o : best;
        }
        int wm = 1023 - (int)(best & 1023u);
        if (lane == 0) idxout[outbase + it] = wm;
        int jj = wm >> 6;                 // wave-uniform
        bool me = (lane == (wm & 63));
        switch (jj) {
          case 0:  kk[0]  = me ? 0ull : kk[0];  break;
          case 1:  kk[1]  = me ? 0ull : kk[1];  break;
          case 2:  kk[2]  = me ? 0ull : kk[2];  break;
          case 3:  kk[3]  = me ? 0ull : kk[3];  break;
          case 4:  kk[4]  = me ? 0ull : kk[4];  break;
          case 5:  kk[5]  = me ? 0ull : kk[5];  break;
          case 6:  kk[6]  = me ? 0ull : kk[6];  break;
          case 7:  kk[7]  = me ? 0ull : kk[7];  break;
          case 8:  kk[8]  = me ? 0ull : kk[8];  break;
          case 9:  kk[9]  = me ? 0ull : kk[9];  break;
          case 10: kk[10] = me ? 0ull : kk[10]; break;
          default: kk[11] = me ? 0ull : kk[11]; break;
        }
      }
    }
  } else if (blockIdx.x < 1152) {
    // ---------- P/R path ----------
    float4* wLs = (float4*)smem;                        // 1024 entries, 16KB
    float4* wDs = (float4*)(smem + 16384);              // 1024 entries, 16KB
    float4 (*xs)[32] = (float4(*)[32])(smem + 32768);   // [pt][cin], 2KB
    for (int i = tid; i < 1024; i += 256) {
      int cin = i >> 5, c = i & 31;
      float kfL = Wkf[c * 64 + cin], kdL = Wkd[c * 64 + cin];
      float vfL = Wvf[c * 64 + cin], vdL = Wvd[c * 64 + cin];
      wLs[i] = make_float4(kfL, kdL, vfL, vdL);
      wDs[i] = make_float4(Wkf[c * 64 + 32 + cin] - kfL, Wkd[c * 64 + 32 + cin] - kdL,
                           Wvf[c * 64 + 32 + cin] - vfL, Wvd[c * 64 + 32 + cin] - vdL);
    }
    int g = tid >> 6, lane = tid & 63, half = lane >> 5, c = lane & 31;
    int p = (blockIdx.x - 768) * 4 + g;
    int b = p / NPTS, n = p % NPTS;
    for (int t = lane; t < 96; t += 64) {
      float v = y[(b * 96 + t) * NPTS + n];
      ((float*)&xs[g][t / 3])[t % 3] = v;
    }
    __syncthreads();
    const float4* wsel = half ? wDs : wLs;
    float kf0 = 0, kf1 = 0, kf2 = 0, kd0 = 0, kd1 = 0, kd2 = 0;
    float vf0 = 0, vf1 = 0, vf2 = 0, vd0 = 0, vd1 = 0, vd2 = 0;
#pragma unroll 8
    for (int cin = 0; cin < 32; cin++) {
      float4 wv = wsel[(cin << 5) + c];
      float4 xv = xs[g][cin];
      kf0 = fmaf(wv.x, xv.x, kf0); kf1 = fmaf(wv.x, xv.y, kf1); kf2 = fmaf(wv.x, xv.z, kf2);
      kd0 = fmaf(wv.y, xv.x, kd0); kd1 = fmaf(wv.y, xv.y, kd1); kd2 = fmaf(wv.y, xv.z, kd2);
      vf0 = fmaf(wv.z, xv.x, vf0); vf1 = fmaf(wv.z, xv.y, vf1); vf2 = fmaf(wv.z, xv.z, vf2);
      vd0 = fmaf(wv.w, xv.x, vd0); vd1 = fmaf(wv.w, xv.y, vd1); vd2 = fmaf(wv.w, xv.z, vd2);
    }
    float* dst = half ? Rb : Pb;
    size_t base = ((size_t)(b * NPTS + n) * 32 + c) * 12;
    float4* Dp = (float4*)(dst + base);
    Dp[0] = make_float4(kf0, kf1, kf2, kd0);
    Dp[1] = make_float4(kd1, kd2, vf0, vf1);
    Dp[2] = make_float4(vf2, vd0, vd1, vd2);
  } else {
    // ---------- Qx path ----------
    float2* w2 = (float2*)smem;                       // [cin][c] (Wqf, Wqd), 8KB
    float4 (*xs)[32] = (float4(*)[32])(smem + 8192);  // [group][cin], 4KB
    for (int i = tid; i < 1024; i += 256) {
      int cin = i >> 5, c = i & 31;
      w2[i] = make_float2(Wqf[c * 32 + cin], Wqd[c * 32 + cin]);
    }
    int g = tid >> 5, c = tid & 31;
    int p = (blockIdx.x - 1152) * 8 + g;
    int b = p / NPTS, n = p % NPTS;
    for (int t = c; t < 96; t += 32) {
      float v = x[(b * 96 + t) * NPTS + n];
      ((float*)&xs[g][t / 3])[t % 3] = v;
    }
    __syncthreads();
    float pf0 = 0, pf1 = 0, pf2 = 0, pd0 = 0, pd1 = 0, pd2 = 0;
#pragma unroll
    for (int cin = 0; cin < 32; cin++) {
      float2 w = w2[(cin << 5) + c];
      float4 xv = xs[g][cin];
      pf0 = fmaf(w.x, xv.x, pf0); pf1 = fmaf(w.x, xv.y, pf1); pf2 = fmaf(w.x, xv.z, pf2);
      pd0 = fmaf(w.y, xv.x, pd0); pd1 = fmaf(w.y, xv.y, pd1); pd2 = fmaf(w.y, xv.z, pd2);
    }
    float dot = pf0 * pd0 + pf1 * pd1 + pf2 * pd2;
    float dsq = pd0 * pd0 + pd1 * pd1 + pd2 * pd2;
    float q0 = pf0, q1 = pf1, q2 = pf2;
    if (dot < 0.f) {
      float r = 0.8f * dot / (dsq + 1e-6f);
      q0 -= r * pd0; q1 -= r * pd1; q2 -= r * pd2;
    }
    float nrm = sqrtf(q0 * q0 + q1 * q1 + q2 * q2);
    float n2 = nrm * nrm;
#pragma unroll
    for (int m = 1; m <= 16; m <<= 1) n2 += __shfl_xor(n2, m);
    float fac = (nrm / fmaxf(sqrtf(n2), 1e-12f)) / fmaxf(nrm, 1e-12f);
    int base = ((b * 32 + c) * 3) * NPTS + n;
    qx[base] = q0 * fac; qx[base + NPTS] = q1 * fac; qx[base + 2 * NPTS] = q2 * fac;
  }
}

// ---------------- KB: gather + nonlinearity + accumulate ----------------
// grid 1536 x 256thr; block = 1 point; 4 waves/point (6 waves/SIMD for gather-latency
// hiding). Wave w handles neighbors w*4..w*4+3 (2 per lane-half kh).
// Cross-half combine via shfl_xor(32); cross-wave combine via LDS (waves 1..3 publish).
__global__ __launch_bounds__(256) void kb_kv(const float* __restrict__ Pb,
    const float* __restrict__ Rb, const int* __restrict__ idxw,
    float* __restrict__ ksum, float* __restrict__ vsum)
{
  __shared__ float red[3][6][32];
  int tid = threadIdx.x;
  int w = tid >> 6;           // wave 0..3
  int lane = tid & 63, kh = lane >> 5, c = lane & 31;
  int p = blockIdx.x;
  int b = p / NPTS, n = p % NPTS;
  const float4* Rp = (const float4*)(Rb + ((size_t)(b * NPTS + n) * 32 + c) * 12);
  float4 r0 = Rp[0], r1 = Rp[1], r2 = Rp[2];
  int ibase = (b * NPTS + n) * 16 + w * 4 + kh * 2;
  int2 ia = *(const int2*)(idxw + ibase);
  int ms[2] = {ia.x, ia.y};
  float ks0 = 0, ks1 = 0, ks2 = 0, vs0 = 0, vs1 = 0, vs2 = 0;
#pragma unroll
  for (int j = 0; j < 2; j++) {
    const float4* Pp = (const float4*)(Pb + ((size_t)(b * NPTS + ms[j]) * 32 + c) * 12);
    float4 p0 = Pp[0], p1 = Pp[1], p2 = Pp[2];
    float kf0 = p0.x + r0.x, kf1 = p0.y + r0.y, kf2 = p0.z + r0.z;
    float kd0 = p0.w + r0.w, kd1 = p1.x + r1.x, kd2 = p1.y + r1.y;
    float vf0 = p1.z + r1.z, vf1 = p1.w + r1.w, vf2 = p2.x + r2.x;
    float vd0 = p2.y + r2.y, vd1 = p2.z + r2.z, vd2 = p2.w + r2.w;
    float dot = kf0 * kd0 + kf1 * kd1 + kf2 * kd2;
    float dsq = kd0 * kd0 + kd1 * kd1 + kd2 * kd2;
    float k0 = kf0, k1 = kf1, k2 = kf2;
    if (dot < 0.f) { float r = 0.8f * dot / (dsq + 1e-6f); k0 -= r * kd0; k1 -= r * kd1; k2 -= r * kd2; }
    float nrm = sqrtf(k0 * k0 + k1 * k1 + k2 * k2);
    float n2 = nrm * nrm;
#pragma unroll
    for (int mm = 1; mm <= 16; mm <<= 1) n2 += __shfl_xor(n2, mm);
    float fac = (nrm / fmaxf(sqrtf(n2), 1e-12f)) / fmaxf(nrm, 1e-12f);
    ks0 = fmaf(k0, fac, ks0); ks1 = fmaf(k1, fac, ks1); ks2 = fmaf(k2, fac, ks2);
    float dotv = vf0 * vd0 + vf1 * vd1 + vf2 * vd2;
    float dsqv = vd0 * vd0 + vd1 * vd1 + vd2 * vd2;
    float v0 = vf0, v1 = vf1, v2 = vf2;
    if (dotv < 0.f) { float r = 0.8f * dotv / (dsqv + 1e-6f); v0 -= r * vd0; v1 -= r * vd1; v2 -= r * vd2; }
    vs0 += v0; vs1 += v1; vs2 += v2;
  }
  // combine the two lane-halves (this wave's 4 neighbors)
  ks0 += __shfl_xor(ks0, 32); ks1 += __shfl_xor(ks1, 32); ks2 += __shfl_xor(ks2, 32);
  vs0 += __shfl_xor(vs0, 32); vs1 += __shfl_xor(vs1, 32); vs2 += __shfl_xor(vs2, 32);
  // cross-wave combine: waves 1..3 publish, wave 0 accumulates + writes
  if (kh == 0 && w > 0) {
    red[w - 1][0][c] = ks0; red[w - 1][1][c] = ks1; red[w - 1][2][c] = ks2;
    red[w - 1][3][c] = vs0; red[w - 1][4][c] = vs1; red[w - 1][5][c] = vs2;
  }
  __syncthreads();
  if (kh == 0 && w == 0) {
#pragma unroll
    for (int r = 0; r < 3; r++) {
      ks0 += red[r][0][c]; ks1 += red[r][1][c]; ks2 += red[r][2][c];
      vs0 += red[r][3][c]; vs1 += red[r][4][c]; vs2 += red[r][5][c];
    }
    int base = ((b * 32 + c) * 3) * NPTS + n;
    ksum[base] = ks0 * SCALE; ksum[base + NPTS] = ks1 * SCALE; ksum[base + 2 * NPTS] = ks2 * SCALE;
    vsum[base] = vs0; vsum[base + NPTS] = vs1; vsum[base + 2 * NPTS] = vs2;
  }
}

// ---------------- KC: attention via Taylor power-moments ----------------
// |q| <= 1, |s| <= 16/sqrt(96) = 1.633  ->  exp(q*s) Taylor deg-12, remainder < 1e-6.
// Per slice: P_t = sum_m s^t, Q_t = sum_m s^t v  (t<=12); per query: 24-fma Horner.
// One block per slice (192 blocks x 256 threads).
__global__ __launch_bounds__(256) void kc_attn(const float* __restrict__ x,
    const float* __restrict__ qx, const float* __restrict__ ks, const float* __restrict__ vs,
    float* __restrict__ out)
{
  __shared__ float red[4][25];
  __shared__ float AB[26];    // AB[0..12] = c_t*P_t (den coeffs), AB[13..25] = c_t*Q_t (num coeffs)
  int tid = threadIdx.x;
  int sl = blockIdx.x;
  const float* srow = ks + sl * NPTS;
  const float* vrow = vs + sl * NPTS;
  float P[12], Q[13];   // P[t] = sum s^{t+1};  Q[0] = sum v, Q[t] = sum s^t v
#pragma unroll
  for (int t = 0; t < 12; t++) P[t] = 0.f;
#pragma unroll
  for (int t = 0; t < 13; t++) Q[t] = 0.f;
  for (int m = tid; m < NPTS; m += 256) {
    float s = srow[m], v = vrow[m];
    Q[0] += v;
    float pw = s;
#pragma unroll
    for (int t = 0; t < 12; t++) {
      P[t] += pw;
      Q[t + 1] = fmaf(pw, v, Q[t + 1]);
      pw *= s;
    }
  }
#pragma unroll
  for (int off = 1; off <= 32; off <<= 1) {
#pragma unroll
    for (int t = 0; t < 12; t++) P[t] += __shfl_xor(P[t], off);
#pragma unroll
    for (int t = 0; t < 13; t++) Q[t] += __shfl_xor(Q[t], off);
  }
  int lane = tid & 63, wid = tid >> 6;
  if (lane == 0) {
#pragma unroll
    for (int t = 0; t < 12; t++) red[wid][t] = P[t];
#pragma unroll
    for (int t = 0; t < 13; t++) red[wid][12 + t] = Q[t];
  }
  __syncthreads();
  if (tid < 25) {
    float sm = red[0][tid] + red[1][tid] + red[2][tid] + red[3][tid];
    if (tid < 12) AB[1 + tid] = CFACT[1 + tid] * sm;          // A_t = P_t/t!, t=1..12
    else          AB[13 + (tid - 12)] = CFACT[tid - 12] * sm; // B_t = Q_t/t!, t=0..12
  }
  if (tid == 25) AB[0] = (float)NPTS;                          // A_0 = sum s^0
  __syncthreads();
#pragma unroll
  for (int nn = 0; nn < 3; nn++) {
    int n = nn * 256 + tid;
    float q = qx[sl * NPTS + n];
    float den = AB[12], num = AB[25];
#pragma unroll
    for (int t = 11; t >= 0; t--) {
      den = fmaf(den, q, AB[t]);
      num = fmaf(num, q, AB[13 + t]);
    }
    out[sl * NPTS + n] = x[sl * NPTS + n] + num / den;
  }
}

extern "C" void kernel_launch(void* const* d_in, const int* in_sizes, int n_in,
                              void* d_out, int out_size, void* d_ws, size_t ws_size,
                              hipStream_t stream) {
  const float* x   = (const float*)d_in[0];
  const float* y   = (const float*)d_in[1];
  const float* Wqf = (const float*)d_in[2];
  const float* Wqd = (const float*)d_in[3];
  const float* Wkf = (const float*)d_in[4];
  const float* Wkd = (const float*)d_in[5];
  const float* Wvf = (const float*)d_in[6];
  const float* Wvd = (const float*)d_in[7];
  float* out = (float*)d_out;

  float* qx   = (float*)d_ws;            // 147456
  float* ksum = qx + 147456;             // 147456 (pre-scaled by 1/sqrt(96))
  float* vsum = ksum + 147456;           // 147456
  int*   idx  = (int*)(vsum + 147456);   // 24576 ints
  float* Pb   = (float*)(idx + 24576);   // 589824
  float* Rb   = Pb + 589824;             // 589824

  ka_pre <<<1344, 256, 0, stream>>>(x, y, Wqf, Wqd, Wkf, Wkd, Wvf, Wvd, qx, Pb, Rb, idx);
  kb_kv  <<<1536, 256, 0, stream>>>(Pb, Rb, idx, ksum, vsum);
  kc_attn<<<192, 256, 0, stream>>>(x, qx, ksum, vsum, out);
}